// Round 6
// baseline (3440.366 us; speedup 1.0000x reference)
//
#include <hip/hip_runtime.h>
#include <math.h>

#define B_N 4096
#define D_F 2048
#define K_P 512
#define NGMAX 4096
#define MU 0.9f
#define OMU (1.0f - MU)
#define LOG2MU (-0.15200309344504997f)
#define FLTMAX 3.402823466e+38f
#define IMAX 0x7FFFFFFF
#define TILE 64
#define SDPITCH 513

// LDS carve (floats/ints)
#define SMEM_FLOATS (64 * SDPITCH + 64 * 65 + 64)
#define SMEM_INTS (512 + 16)
#define SMEM_BYTES ((SMEM_FLOATS + SMEM_INTS) * 4)

__device__ __forceinline__ bool argless(float v1, int i1, float v2, int i2) {
    return (v1 < v2) || (v1 == v2 && i1 < i2);
}

// DPP min-reduce: lane 63 holds the wave min after the sequence.
template <int CTRL>
__device__ __forceinline__ float dppmin_f(float v) {
    int t = __builtin_amdgcn_update_dpp(__float_as_int(v), __float_as_int(v), CTRL, 0xf, 0xf, false);
    return fminf(v, __int_as_float(t));
}
__device__ __forceinline__ float wave_min_f(float v) {
    v = dppmin_f<0x111>(v);
    v = dppmin_f<0x112>(v);
    v = dppmin_f<0x114>(v);
    v = dppmin_f<0x118>(v);
    v = dppmin_f<0x142>(v);
    v = dppmin_f<0x143>(v);
    return __int_as_float(__builtin_amdgcn_readlane(__float_as_int(v), 63));
}

// Exact first-index wave argmin over 8 per-lane values (index = r*64+lane).
__device__ __forceinline__ void wave_argmin8(const float v[8], float& mv, int& mi) {
    float m01 = (v[1] < v[0]) ? v[1] : v[0]; int i01 = (v[1] < v[0]) ? 1 : 0;
    float m23 = (v[3] < v[2]) ? v[3] : v[2]; int i23 = (v[3] < v[2]) ? 3 : 2;
    float m45 = (v[5] < v[4]) ? v[5] : v[4]; int i45 = (v[5] < v[4]) ? 5 : 4;
    float m67 = (v[7] < v[6]) ? v[7] : v[6]; int i67 = (v[7] < v[6]) ? 7 : 6;
    float m03 = (m23 < m01) ? m23 : m01; int i03 = (m23 < m01) ? i23 : i01;
    float m47 = (m67 < m45) ? m67 : m45; int i47 = (m67 < m45) ? i67 : i45;
    float lm = (m47 < m03) ? m47 : m03; int lr = (m47 < m03) ? i47 : i03;
    float m = wave_min_f(lm);
    unsigned long long cm = __ballot(lm == m);
    int ks = IMAX;
    do {
        int l = (int)__builtin_ctzll(cm);
        cm &= cm - 1;
        int key = (__builtin_amdgcn_readlane(lr, l) << 6) | l;
        ks = min(ks, key);
    } while (cm);
    mv = m; mi = ks;
}

// -------- prep: compact gated indices, counts --------
__global__ void k_prep(const int* __restrict__ g, int* __restrict__ gsteps,
                       int* __restrict__ scal) {
    __shared__ int s[1024];
    __shared__ int base;
    int tid = threadIdx.x;
    if (tid == 0) base = 0;
    __syncthreads();
    for (int c = 0; c < 4; ++c) {
        int i = c * 1024 + tid;
        int gi = (g[i] != 0) ? 1 : 0;
        s[tid] = gi;
        __syncthreads();
        for (int off = 1; off < 1024; off <<= 1) {
            int v = (tid >= off) ? s[tid - off] : 0;
            __syncthreads();
            s[tid] += v;
            __syncthreads();
        }
        int pos = base + s[tid] - 1;
        if (gi) gsteps[pos] = i;
        __syncthreads();
        if (tid == 1023) base += s[1023];
        __syncthreads();
    }
    if (tid == 0) { scal[0] = base; scal[1] = B_N - base; }
}

// -------- row squared norms (wave per row) --------
__global__ void k_rownorm(const float* __restrict__ src, float* __restrict__ dst, int nrows) {
    int row = blockIdx.x * 4 + (threadIdx.x >> 6);
    int lane = threadIdx.x & 63;
    if (row >= nrows) return;
    const float* p = src + (size_t)row * D_F;
    float acc = 0.f;
    for (int d0 = lane * 4; d0 < D_F; d0 += 256) {
        float4 v = *(const float4*)(p + d0);
        acc += v.x * v.x + v.y * v.y + v.z * v.z + v.w * v.w;
    }
    for (int off = 32; off; off >>= 1) acc += __shfl_xor(acc, off);
    if (lane == 0) dst[row] = acc;
}

// -------- anomaly column sums (partials) --------
__global__ void k_colsum(const float* __restrict__ Z, const int* __restrict__ g,
                         float* __restrict__ anom_part) {
    int d = blockIdx.x * 256 + threadIdx.x;
    int rc = blockIdx.y;
    float acc = 0.f;
    int r0 = rc * 128;
    for (int r = r0; r < r0 + 128; ++r) {
        if (g[r] == 0) acc += Z[(size_t)r * D_F + d];
    }
    anom_part[(size_t)rc * D_F + d] = acc;
}

// -------- finalize m_a --------
__global__ void k_fin_ma(const float* __restrict__ anom_part, const float* __restrict__ ma_in,
                         const int* __restrict__ scal, float* __restrict__ m_a_used,
                         float* __restrict__ scal_f) {
    __shared__ float red[1024];
    int tid = threadIdx.x;
    int na = scal[1];
    float m2 = 0.f;
    for (int dd = tid; dd < D_F; dd += 1024) {
        float s = 0.f;
        for (int c = 0; c < 32; ++c) s += anom_part[(size_t)c * D_F + dd];
        float v = (na > 0) ? (s / (float)na) : ma_in[dd];
        m_a_used[dd] = v;
        m2 += v * v;
    }
    red[tid] = m2;
    __syncthreads();
    for (int off = 512; off; off >>= 1) {
        if (tid < off) red[tid] += red[tid + off];
        __syncthreads();
    }
    if (tid == 0) scal_f[0] = red[0];
}

// -------- GEMM (NT: C = A * B^T), 64x64 tile, BK=16, 256 thr, 4x4 micro --------
template <int MODE>
__global__ void k_gemm(const float* __restrict__ Z, const float* __restrict__ P0,
                       const float* __restrict__ Pn, const int* __restrict__ gsteps,
                       const int* __restrict__ scal, float* __restrict__ Gram,
                       float* __restrict__ Dot, float* __restrict__ Dotf) {
    int ng = scal[0];
    int M = (MODE == 0) ? (ng + K_P) : B_N;
    int N = (MODE == 0) ? ng : K_P;
    int mb = blockIdx.y * 64, nb = blockIdx.x * 64;
    if (mb >= M || nb >= N) return;
    if (MODE == 0 && (mb + 64 <= ng) && (nb + 64 <= mb)) return;

    __shared__ float As[16][68];
    __shared__ float Bs[16][68];
    __shared__ const float* rowA[64];
    __shared__ const float* rowB[64];

    int tid = threadIdx.x;
    if (tid < 64) {
        int gm = mb + tid;
        const float* pa = nullptr;
        if (MODE == 0) {
            if (gm < ng) pa = Z + (size_t)gsteps[gm] * D_F;
            else if (gm < ng + K_P) pa = P0 + (size_t)(gm - ng) * D_F;
        } else {
            if (gm < B_N) pa = Z + (size_t)gm * D_F;
        }
        rowA[tid] = pa;
    } else if (tid < 128) {
        int t = tid - 64;
        int gn = nb + t;
        const float* pb = nullptr;
        if (MODE == 0) { if (gn < ng) pb = Z + (size_t)gsteps[gn] * D_F; }
        else { if (gn < K_P) pb = Pn + (size_t)gn * D_F; }
        rowB[t] = pb;
    }
    __syncthreads();

    int r = tid & 63, kq = tid >> 6;
    int tm = tid >> 4, tn = tid & 15;
    const float* pa = rowA[r];
    const float* pb = rowB[r];

    float acc[4][4] = {};
    for (int k0 = 0; k0 < D_F; k0 += 16) {
        float4 av = pa ? *(const float4*)(pa + k0 + kq * 4) : make_float4(0.f, 0.f, 0.f, 0.f);
        float4 bv = pb ? *(const float4*)(pb + k0 + kq * 4) : make_float4(0.f, 0.f, 0.f, 0.f);
        __syncthreads();
        As[kq * 4 + 0][r] = av.x; As[kq * 4 + 1][r] = av.y;
        As[kq * 4 + 2][r] = av.z; As[kq * 4 + 3][r] = av.w;
        Bs[kq * 4 + 0][r] = bv.x; Bs[kq * 4 + 1][r] = bv.y;
        Bs[kq * 4 + 2][r] = bv.z; Bs[kq * 4 + 3][r] = bv.w;
        __syncthreads();
#pragma unroll
        for (int kk = 0; kk < 16; ++kk) {
            float4 a = *(const float4*)&As[kk][tm * 4];
            float4 b = *(const float4*)&Bs[kk][tn * 4];
            float aa[4] = {a.x, a.y, a.z, a.w};
            float bb[4] = {b.x, b.y, b.z, b.w};
#pragma unroll
            for (int i = 0; i < 4; ++i)
#pragma unroll
                for (int j = 0; j < 4; ++j) acc[i][j] += aa[i] * bb[j];
        }
    }

#pragma unroll
    for (int i = 0; i < 4; ++i) {
        int gm = mb + tm * 4 + i;
        if (gm >= M) continue;
        float* crow;
        if (MODE == 0)
            crow = (gm < ng) ? (Gram + (size_t)gm * NGMAX) : (Dot + (size_t)(gm - ng) * NGMAX);
        else
            crow = Dotf + (size_t)gm * K_P;
#pragma unroll
        for (int j = 0; j < 4; ++j) {
            int gn = nb + tn * 4 + j;
            if (gn < N) crow[gn] = acc[i][j];
        }
    }
}

// -------- tiled sequential scan: speculative cross-step pipeline --------
__global__ __launch_bounds__(512, 1)
void k_scan_tiled(const float* __restrict__ Gram, const float* __restrict__ Dot,
                  const float* __restrict__ pn2_0, const float* __restrict__ zn2,
                  const int* __restrict__ gsteps, const int* __restrict__ scal,
                  int* __restrict__ winlist, int* __restrict__ clist,
                  int* __restrict__ cnt_out) {
    extern __shared__ char smem_raw[];
    float* sdot = (float*)smem_raw;             // [64][SDPITCH] transposed: sdot[x][k]
    float* sgram = sdot + 64 * SDPITCH;         // [64][65]
    float* szn2 = sgram + 64 * 65;              // [64]
    int* rowcnt = (int*)(szn2 + 64);            // [512] global win counts
    int* listlen = rowcnt + 512;                // [8] per-wave correction-list lengths

    int tid = threadIdx.x;
    int lane = tid & 63;
    int wave = tid >> 6;
    int ng = scal[0];

    rowcnt[tid] = 0;
    if (tid < 8) listlen[tid] = 0;
    __syncthreads();

    // wave-0 lane-private state: lane owns prototypes k = r*64 + lane
    float pn2r[8];
    if (wave == 0) {
#pragma unroll
        for (int r = 0; r < 8; ++r) pn2r[r] = pn2_0[r * 64 + lane];
    }

    int ntiles = (ng + TILE - 1) / TILE;
    for (int T = 0; T < ntiles; ++T) {
        int j0 = T * TILE;
        int tlen = min(TILE, ng - j0);

        // ---- stage Dot0 tile (transposed) with mu^c scale fused ----
        {
            const float* basep = Dot + (size_t)(wave * 64) * NGMAX + j0 + lane;
            float* sb = sdot + lane * SDPITCH + wave * 64;
#pragma unroll 8
            for (int rr = 0; rr < 64; ++rr) {
                float sc = exp2f((float)rowcnt[wave * 64 + rr] * LOG2MU);
                sb[rr] = basep[(size_t)rr * NGMAX] * sc;
            }
        }
        // ---- corrections: wave streams its own flat list ----
        {
            int len = listlen[wave];
            const int* cl = clist + (size_t)wave * NGMAX;
            for (int i = 0; i < len; ++i) {
                int a = cl[i];
                int row = a & 511;
                int gq = (a >> 9) & 2047;
                int t = (a >> 20) & 4095;
                int c = rowcnt[row];
                float wq = OMU * exp2f((float)(c - 1 - gq) * LOG2MU);
                float gv = Gram[(size_t)t * NGMAX + j0 + lane];
                sdot[lane * SDPITCH + row] += wq * gv;
            }
        }
        // gram diag block + zn2
        {
            int t = tid >> 3, xo = (tid & 7) * 8;
            const float* src = Gram + (size_t)(j0 + t) * NGMAX + j0 + xo;
            float4 a = *(const float4*)(src);
            float4 b = *(const float4*)(src + 4);
            float* dst = sgram + t * 65 + xo;
            dst[0] = a.x; dst[1] = a.y; dst[2] = a.z; dst[3] = a.w;
            dst[4] = b.x; dst[5] = b.y; dst[6] = b.z; dst[7] = b.w;
        }
        if (tid < TILE) {
            szn2[tid] = (tid < tlen) ? zn2[gsteps[j0 + tid]] : 0.f;
        }
        __syncthreads();

        // ---- phase S (wave 0 only): speculative pipeline ----
        if (wave == 0) {
            float d8[8], pv[8], nv[8];
            {
                int c1 = (tlen > 1) ? 1 : 0;
                int c2 = (tlen > 2) ? 2 : c1;
                const float* b0 = sdot;
                const float* b1 = sdot + c1 * SDPITCH;
                const float* b2 = sdot + c2 * SDPITCH;
#pragma unroll
                for (int r = 0; r < 8; ++r) {
                    d8[r] = b0[r * 64 + lane];
                    pv[r] = b1[r * 64 + lane];
                    nv[r] = b2[r * 64 + lane];
                }
            }
            float z2c = szn2[0];
            float g1c = sgram[1];       // G[0][1] (masked when invalid)
            float g2c = sgram[2];       // G[0][2]
            float g3c = 0.f;            // unused at iter 0
            float t1v; int t1i;
            {
                float v0[8];
#pragma unroll
                for (int r = 0; r < 8; ++r) v0[r] = pn2r[r] - 2.f * d8[r];
                wave_argmin8(v0, t1v, t1i);
            }
            int ks_prev = -1;
            float vu_s = FLTMAX;
            int stw_reg = 0;

            for (int jl = 0; jl < tlen; ++jl) {
                const bool hn = (jl + 1 < tlen);
                const bool h2 = (jl + 2 < tlen);
                const bool h3 = (jl + 3 < tlen);
                // (a) issue prefetch of col jl+3
                float nvn[8];
                {
                    int cp = h3 ? (jl + 3) : (tlen - 1);
                    const float* cb = sdot + cp * SDPITCH;
#pragma unroll
                    for (int r = 0; r < 8; ++r) nvn[r] = cb[r * 64 + lane];
                }
                // per-lane RMW operand + scalar prefetches for next iter
                int xr = jl + 4 + lane;
                float grmw = sgram[jl * 65 + ((xr < 64) ? xr : 63)];
                int jn = hn ? (jl + 1) : jl;
                float z2n = szn2[jn];
                float g1n = sgram[jn * 65 + ((jn + 1 < 64) ? jn + 1 : 63)];
                float g2n = sgram[jn * 65 + ((jn + 2 < 64) ? jn + 2 : 63)];
                float g3n = sgram[jl * 65 + ((jl + 3 < 64) ? jl + 3 : 63)];
                // (a2) fix_a: apply step jl-1 to nv (col jl+2), owner(ks_prev)
                if (ks_prev >= 0 && h2) {
                    int pl = ks_prev & 63, pr = ks_prev >> 6;
                    bool pmine = (lane == pl);
#pragma unroll
                    for (int r = 0; r < 8; ++r)
                        if (pmine && r == pr) nv[r] = MU * nv[r] + OMU * g3c;
                }
                // (b) snapshot for col jl+1 reduce (pre-fix1 => stale missing step jl)
                float vv[8];
                if (hn) {
#pragma unroll
                    for (int r = 0; r < 8; ++r) vv[r] = pn2r[r] - 2.f * pv[r];
                }
                // (c) resolve step jl
                int ks;
                if (t1i == ks_prev) {   // rare: stale argmin collided with updated row
                    float vt[8];
#pragma unroll
                    for (int r = 0; r < 8; ++r) vt[r] = pn2r[r] - 2.f * d8[r];
                    float dv;
                    wave_argmin8(vt, dv, ks);   // d8 is fully true -> exact
                } else {
                    ks = (ks_prev >= 0 && argless(vu_s, ks_prev, t1v, t1i)) ? ks_prev : t1i;
                }
                stw_reg = (lane == jl) ? ks : stw_reg;
                int wlane = ks & 63, wr = ks >> 6;
                bool mine = (lane == wlane);
                // (d) owner: pn2 update, fix1 on pv (col jl+1), vu for next combine
                float vu_v = FLTMAX;
#pragma unroll
                for (int r = 0; r < 8; ++r) {
                    if (mine && r == wr) {
                        pn2r[r] = MU * MU * pn2r[r] + 2.f * MU * OMU * d8[r] + OMU * OMU * z2c;
                        if (hn) {
                            pv[r] = MU * pv[r] + OMU * g1c;
                            vu_v = pn2r[r] - 2.f * pv[r];
                        }
                    }
                }
                vu_s = __int_as_float(__builtin_amdgcn_readlane(__float_as_int(vu_v), wlane));
                // (e) throughput reduce for col jl+1 (used next iter)
                if (hn) wave_argmin8(vv, t1v, t1i);
                // (f) RMW row ks, cols >= jl+4
                if (xr < tlen) {
                    float* dp = sdot + xr * SDPITCH + ks;
                    *dp = MU * *dp + OMU * grmw;
                }
                // (g) fix_b: apply step jl to nv (col jl+2)
                if (h2) {
#pragma unroll
                    for (int r = 0; r < 8; ++r)
                        if (mine && r == wr) nv[r] = MU * nv[r] + OMU * g2c;
                }
                // (h) shift pipeline
#pragma unroll
                for (int r = 0; r < 8; ++r) { d8[r] = pv[r]; pv[r] = nv[r]; nv[r] = nvn[r]; }
                ks_prev = ks;
                z2c = z2n; g1c = g1n; g2c = g2n; g3c = g3n;
            }

            // ---- post-pass: ranks, winlist append, per-wave correction lists ----
            int wj = stw_reg;
            bool valid = (lane < tlen);
            int myL = wj >> 6;
            int rank = 0, mrow = 0, lpos = 0, lcnt = 0;
            for (int i = 0; i < tlen; ++i) {
                int wi = __builtin_amdgcn_readlane(wj, i);
                if (valid && wi == wj) {
                    mrow++;
                    if (i < lane) rank++;
                }
                if (valid && (wi >> 6) == myL) {
                    lcnt++;
                    if (i < lane) lpos++;
                }
            }
            bool first = valid && (rank == 0);
            bool firstL = valid && (lpos == 0);
            int base = rowcnt[wj];
            int lbase = listlen[myL];
            if (valid) {
                int gq = base + rank;
                winlist[(size_t)wj * NGMAX + gq] = j0 + lane;
                clist[(size_t)myL * NGMAX + lbase + lpos] =
                    wj | (gq << 9) | ((j0 + lane) << 20);
            }
            if (first) rowcnt[wj] += mrow;
            if (firstL) listlen[myL] += lcnt;
        }
        __syncthreads();
    }

    cnt_out[tid] = rowcnt[tid];
}

// -------- materialize final prototypes via win lists (block per prototype) --------
__global__ void k_mat(const float* __restrict__ Z, const float* __restrict__ P0,
                      const int* __restrict__ gsteps, const int* __restrict__ winlist,
                      const int* __restrict__ cnt, float* __restrict__ Pn) {
    int k = blockIdx.x;
    int tid = threadIdx.x;
    int c = cnt[k];
    float bw = exp2f((float)c * LOG2MU);
    const float4* p0r = (const float4*)(P0 + (size_t)k * D_F);
    float4 a0 = p0r[tid], a1 = p0r[tid + 256];
    a0.x *= bw; a0.y *= bw; a0.z *= bw; a0.w *= bw;
    a1.x *= bw; a1.y *= bw; a1.z *= bw; a1.w *= bw;
    const int* wl = winlist + (size_t)k * NGMAX;
    float w = OMU;
    for (int q = c - 1; q >= 0; --q) {
        int t = wl[q];
        const float4* zr = (const float4*)(Z + (size_t)gsteps[t] * D_F);
        float4 z0 = zr[tid], z1 = zr[tid + 256];
        a0.x += w * z0.x; a0.y += w * z0.y; a0.z += w * z0.z; a0.w += w * z0.w;
        a1.x += w * z1.x; a1.y += w * z1.y; a1.z += w * z1.z; a1.w += w * z1.w;
        w *= MU;
    }
    float4* pnr = (float4*)(Pn + (size_t)k * D_F);
    pnr[tid] = a0;
    pnr[tid + 256] = a1;
}

// -------- top-3 nearest + pull-loss row sums (wave per row) --------
__global__ void k_top3(const float* __restrict__ Dotf, const float* __restrict__ pn2f,
                       const float* __restrict__ Z, const float* __restrict__ Pn,
                       float* __restrict__ rowsum) {
    int row = blockIdx.x * 4 + (threadIdx.x >> 6);
    int lane = threadIdx.x & 63;
    float bv0 = FLTMAX, bv1 = FLTMAX, bv2 = FLTMAX;
    int bi0 = IMAX, bi1 = IMAX, bi2 = IMAX;
    for (int t = 0; t < 8; ++t) {
        int k = lane + 64 * t;
        float v = pn2f[k] - 2.f * Dotf[(size_t)row * K_P + k];
        if (argless(v, k, bv0, bi0)) {
            bv2 = bv1; bi2 = bi1; bv1 = bv0; bi1 = bi0; bv0 = v; bi0 = k;
        } else if (argless(v, k, bv1, bi1)) {
            bv2 = bv1; bi2 = bi1; bv1 = v; bi1 = k;
        } else if (argless(v, k, bv2, bi2)) {
            bv2 = v; bi2 = k;
        }
    }
    for (int off = 32; off; off >>= 1) {
        float a0 = bv0, a1 = bv1, a2 = bv2;
        int x0 = bi0, x1 = bi1, x2 = bi2;
        float b0 = __shfl_xor(bv0, off), b1 = __shfl_xor(bv1, off), b2 = __shfl_xor(bv2, off);
        int y0 = __shfl_xor(bi0, off), y1 = __shfl_xor(bi1, off), y2 = __shfl_xor(bi2, off);
        float nv[3]; int ni[3];
#pragma unroll
        for (int s = 0; s < 3; ++s) {
            bool ta = argless(a0, x0, b0, y0);
            nv[s] = ta ? a0 : b0;
            ni[s] = ta ? x0 : y0;
            if (ta) { a0 = a1; x0 = x1; a1 = a2; x1 = x2; a2 = FLTMAX; x2 = IMAX; }
            else    { b0 = b1; y0 = y1; b1 = b2; y1 = y2; b2 = FLTMAX; y2 = IMAX; }
        }
        bv0 = nv[0]; bv1 = nv[1]; bv2 = nv[2];
        bi0 = ni[0]; bi1 = ni[1]; bi2 = ni[2];
    }
    const float* pa = Pn + (size_t)bi0 * D_F;
    const float* pb = Pn + (size_t)bi1 * D_F;
    const float* pc = Pn + (size_t)bi2 * D_F;
    const float* zr = Z + (size_t)row * D_F;
    const float third = 1.f / 3.f;
    float acc = 0.f;
    for (int d0 = lane * 4; d0 < D_F; d0 += 256) {
        float4 z = *(const float4*)(zr + d0);
        float4 A = *(const float4*)(pa + d0);
        float4 Bv = *(const float4*)(pb + d0);
        float4 C = *(const float4*)(pc + d0);
        float m, df;
        m = (A.x + Bv.x + C.x) * third; df = z.x - m; acc += df * df;
        m = (A.y + Bv.y + C.y) * third; df = z.y - m; acc += df * df;
        m = (A.z + Bv.z + C.z) * third; df = z.z - m; acc += df * df;
        m = (A.w + Bv.w + C.w) * third; df = z.w - m; acc += df * df;
    }
    for (int off = 32; off; off >>= 1) acc += __shfl_xor(acc, off);
    if (lane == 0) rowsum[row] = acc;
}

// -------- push-loss row values (wave per row) --------
__global__ void k_push(const float* __restrict__ Z, const float* __restrict__ m_a_used,
                       const float* __restrict__ zn2, const float* __restrict__ scal_f,
                       float* __restrict__ rowpush) {
    int row = blockIdx.x * 4 + (threadIdx.x >> 6);
    int lane = threadIdx.x & 63;
    const float* zr = Z + (size_t)row * D_F;
    float acc = 0.f;
    for (int d0 = lane * 4; d0 < D_F; d0 += 256) {
        float4 z = *(const float4*)(zr + d0);
        float4 m = *(const float4*)(m_a_used + d0);
        acc += z.x * m.x + z.y * m.y + z.z * m.z + z.w * m.w;
    }
    for (int off = 32; off; off >>= 1) acc += __shfl_xor(acc, off);
    if (lane == 0) {
        float d2 = zn2[row] - 2.f * acc + scal_f[0];
        float dist = sqrtf(fmaxf(d2, 0.f));
        rowpush[row] = fmaxf(1.f - dist, 0.f);
    }
}

// -------- final combine --------
__global__ void k_final(const float* __restrict__ rowsum, const float* __restrict__ rowpush,
                        const int* __restrict__ scal, float* __restrict__ out) {
    __shared__ float red[1024];
    int tid = threadIdx.x;
    float s = 0.f;
    for (int i = tid; i < B_N; i += 1024) s += rowsum[i];
    red[tid] = s;
    __syncthreads();
    for (int off = 512; off; off >>= 1) {
        if (tid < off) red[tid] += red[tid + off];
        __syncthreads();
    }
    float pull = red[0] / ((float)B_N * (float)D_F);
    __syncthreads();
    float p = 0.f;
    for (int i = tid; i < B_N; i += 1024) p += rowpush[i];
    red[tid] = p;
    __syncthreads();
    for (int off = 512; off; off >>= 1) {
        if (tid < off) red[tid] += red[tid + off];
        __syncthreads();
    }
    if (tid == 0) {
        float lpush = (scal[1] > 0) ? (red[0] / (float)B_N) : 0.f;
        out[0] = pull + 0.5f * lpush;
    }
}

extern "C" void kernel_launch(void* const* d_in, const int* in_sizes, int n_in,
                              void* d_out, int out_size, void* d_ws, size_t ws_size,
                              hipStream_t stream) {
    const float* Z = (const float*)d_in[0];
    const int* g = (const int*)d_in[1];
    const float* P0 = (const float*)d_in[2];
    const float* ma_in = (const float*)d_in[4];
    float* out = (float*)d_out;

    float* ws = (float*)d_ws;
    float* Gram = ws;                                   // 16M floats
    float* Dotf = ws;                                   // overlaps Gram (Gram dead by then)
    float* Dot = ws + (size_t)NGMAX * NGMAX;            // 512*4096 (read-only after GEMM)
    float* Pn = Dot + (size_t)K_P * NGMAX;              // 512*2048
    float* zn2 = Pn + (size_t)K_P * D_F;                // 4096
    float* pn2_0 = zn2 + B_N;                           // 512
    float* pn2f = pn2_0 + K_P;                          // 512
    float* anom_part = pn2f + K_P;                      // 32*2048
    float* m_a_used = anom_part + 32 * D_F;             // 2048
    float* rowsum = m_a_used + D_F;                     // 4096
    float* rowpush = rowsum + B_N;                      // 4096
    float* scal_f = rowpush + B_N;                      // 16
    int* gsteps = (int*)(scal_f + 16);                  // 4096
    int* cnt = gsteps + B_N;                            // 512
    int* scal = cnt + K_P;                              // 16
    int* winlist = scal + 16;                           // 512*4096 (8 MB)
    int* clist = winlist + (size_t)K_P * NGMAX;         // 8*4096 (128 KB)

    hipFuncSetAttribute((const void*)k_scan_tiled,
                        hipFuncAttributeMaxDynamicSharedMemorySize, SMEM_BYTES);

    k_prep<<<1, 1024, 0, stream>>>(g, gsteps, scal);
    k_rownorm<<<(B_N + 3) / 4, 256, 0, stream>>>(Z, zn2, B_N);
    k_rownorm<<<(K_P + 3) / 4, 256, 0, stream>>>(P0, pn2_0, K_P);
    k_colsum<<<dim3(D_F / 256, 32), 256, 0, stream>>>(Z, g, anom_part);
    k_fin_ma<<<1, 1024, 0, stream>>>(anom_part, ma_in, scal, m_a_used, scal_f);
    k_gemm<0><<<dim3(NGMAX / 64, (NGMAX + K_P) / 64), 256, 0, stream>>>(
        Z, P0, Pn, gsteps, scal, Gram, Dot, Dotf);
    k_scan_tiled<<<1, 512, SMEM_BYTES, stream>>>(Gram, Dot, pn2_0, zn2, gsteps, scal,
                                                 winlist, clist, cnt);
    k_mat<<<K_P, 256, 0, stream>>>(Z, P0, gsteps, winlist, cnt, Pn);
    k_rownorm<<<(K_P + 3) / 4, 256, 0, stream>>>(Pn, pn2f, K_P);
    k_gemm<1><<<dim3(K_P / 64, B_N / 64), 256, 0, stream>>>(
        Z, P0, Pn, gsteps, scal, Gram, Dot, Dotf);
    k_top3<<<B_N / 4, 256, 0, stream>>>(Dotf, pn2f, Z, Pn, rowsum);
    k_push<<<B_N / 4, 256, 0, stream>>>(Z, m_a_used, zn2, scal_f, rowpush);
    k_final<<<1, 1024, 0, stream>>>(rowsum, rowpush, scal, out);
}

// Round 7
// 3211.298 us; speedup vs baseline: 1.0713x; 1.0713x over previous
//
#include <hip/hip_runtime.h>
#include <math.h>

#define B_N 4096
#define D_F 2048
#define K_P 512
#define NGMAX 4096
#define MU 0.9f
#define OMU (1.0f - MU)
#define LOG2MU (-0.15200309344504997f)
#define FLTMAX 3.402823466e+38f
#define IMAX 0x7FFFFFFF
#define TILE 64
#define SDPITCH 513

// LDS carve (floats/ints)
#define SMEM_FLOATS (64 * SDPITCH + 64 * 65 + 64)
#define SMEM_INTS (512 + 8 + 32)
#define SMEM_BYTES ((SMEM_FLOATS + SMEM_INTS) * 4)

__device__ __forceinline__ bool argless(float v1, int i1, float v2, int i2) {
    return (v1 < v2) || (v1 == v2 && i1 < i2);
}

// DPP min-reduce: lane 63 holds the wave min after the sequence.
template <int CTRL>
__device__ __forceinline__ float dppmin_f(float v) {
    int t = __builtin_amdgcn_update_dpp(__float_as_int(v), __float_as_int(v), CTRL, 0xf, 0xf, false);
    return fminf(v, __int_as_float(t));
}
__device__ __forceinline__ float wave_min_f(float v) {
    v = dppmin_f<0x111>(v);
    v = dppmin_f<0x112>(v);
    v = dppmin_f<0x114>(v);
    v = dppmin_f<0x118>(v);
    v = dppmin_f<0x142>(v);
    v = dppmin_f<0x143>(v);
    return __int_as_float(__builtin_amdgcn_readlane(__float_as_int(v), 63));
}

// -------- prep: compact gated indices, counts --------
__global__ void k_prep(const int* __restrict__ g, int* __restrict__ gsteps,
                       int* __restrict__ scal) {
    __shared__ int s[1024];
    __shared__ int base;
    int tid = threadIdx.x;
    if (tid == 0) base = 0;
    __syncthreads();
    for (int c = 0; c < 4; ++c) {
        int i = c * 1024 + tid;
        int gi = (g[i] != 0) ? 1 : 0;
        s[tid] = gi;
        __syncthreads();
        for (int off = 1; off < 1024; off <<= 1) {
            int v = (tid >= off) ? s[tid - off] : 0;
            __syncthreads();
            s[tid] += v;
            __syncthreads();
        }
        int pos = base + s[tid] - 1;
        if (gi) gsteps[pos] = i;
        __syncthreads();
        if (tid == 1023) base += s[1023];
        __syncthreads();
    }
    if (tid == 0) { scal[0] = base; scal[1] = B_N - base; }
}

// -------- row squared norms (wave per row) --------
__global__ void k_rownorm(const float* __restrict__ src, float* __restrict__ dst, int nrows) {
    int row = blockIdx.x * 4 + (threadIdx.x >> 6);
    int lane = threadIdx.x & 63;
    if (row >= nrows) return;
    const float* p = src + (size_t)row * D_F;
    float acc = 0.f;
    for (int d0 = lane * 4; d0 < D_F; d0 += 256) {
        float4 v = *(const float4*)(p + d0);
        acc += v.x * v.x + v.y * v.y + v.z * v.z + v.w * v.w;
    }
    for (int off = 32; off; off >>= 1) acc += __shfl_xor(acc, off);
    if (lane == 0) dst[row] = acc;
}

// -------- anomaly column sums (partials) --------
__global__ void k_colsum(const float* __restrict__ Z, const int* __restrict__ g,
                         float* __restrict__ anom_part) {
    int d = blockIdx.x * 256 + threadIdx.x;
    int rc = blockIdx.y;
    float acc = 0.f;
    int r0 = rc * 128;
    for (int r = r0; r < r0 + 128; ++r) {
        if (g[r] == 0) acc += Z[(size_t)r * D_F + d];
    }
    anom_part[(size_t)rc * D_F + d] = acc;
}

// -------- finalize m_a --------
__global__ void k_fin_ma(const float* __restrict__ anom_part, const float* __restrict__ ma_in,
                         const int* __restrict__ scal, float* __restrict__ m_a_used,
                         float* __restrict__ scal_f) {
    __shared__ float red[1024];
    int tid = threadIdx.x;
    int na = scal[1];
    float m2 = 0.f;
    for (int dd = tid; dd < D_F; dd += 1024) {
        float s = 0.f;
        for (int c = 0; c < 32; ++c) s += anom_part[(size_t)c * D_F + dd];
        float v = (na > 0) ? (s / (float)na) : ma_in[dd];
        m_a_used[dd] = v;
        m2 += v * v;
    }
    red[tid] = m2;
    __syncthreads();
    for (int off = 512; off; off >>= 1) {
        if (tid < off) red[tid] += red[tid + off];
        __syncthreads();
    }
    if (tid == 0) scal_f[0] = red[0];
}

// -------- GEMM (NT: C = A * B^T), 64x64 tile, BK=16, 256 thr, 4x4 micro --------
template <int MODE>
__global__ void k_gemm(const float* __restrict__ Z, const float* __restrict__ P0,
                       const float* __restrict__ Pn, const int* __restrict__ gsteps,
                       const int* __restrict__ scal, float* __restrict__ Gram,
                       float* __restrict__ Dot, float* __restrict__ Dotf) {
    int ng = scal[0];
    int M = (MODE == 0) ? (ng + K_P) : B_N;
    int N = (MODE == 0) ? ng : K_P;
    int mb = blockIdx.y * 64, nb = blockIdx.x * 64;
    if (mb >= M || nb >= N) return;
    if (MODE == 0 && (mb + 64 <= ng) && (nb + 64 <= mb)) return;

    __shared__ float As[16][68];
    __shared__ float Bs[16][68];
    __shared__ const float* rowA[64];
    __shared__ const float* rowB[64];

    int tid = threadIdx.x;
    if (tid < 64) {
        int gm = mb + tid;
        const float* pa = nullptr;
        if (MODE == 0) {
            if (gm < ng) pa = Z + (size_t)gsteps[gm] * D_F;
            else if (gm < ng + K_P) pa = P0 + (size_t)(gm - ng) * D_F;
        } else {
            if (gm < B_N) pa = Z + (size_t)gm * D_F;
        }
        rowA[tid] = pa;
    } else if (tid < 128) {
        int t = tid - 64;
        int gn = nb + t;
        const float* pb = nullptr;
        if (MODE == 0) { if (gn < ng) pb = Z + (size_t)gsteps[gn] * D_F; }
        else { if (gn < K_P) pb = Pn + (size_t)gn * D_F; }
        rowB[t] = pb;
    }
    __syncthreads();

    int r = tid & 63, kq = tid >> 6;
    int tm = tid >> 4, tn = tid & 15;
    const float* pa = rowA[r];
    const float* pb = rowB[r];

    float acc[4][4] = {};
    for (int k0 = 0; k0 < D_F; k0 += 16) {
        float4 av = pa ? *(const float4*)(pa + k0 + kq * 4) : make_float4(0.f, 0.f, 0.f, 0.f);
        float4 bv = pb ? *(const float4*)(pb + k0 + kq * 4) : make_float4(0.f, 0.f, 0.f, 0.f);
        __syncthreads();
        As[kq * 4 + 0][r] = av.x; As[kq * 4 + 1][r] = av.y;
        As[kq * 4 + 2][r] = av.z; As[kq * 4 + 3][r] = av.w;
        Bs[kq * 4 + 0][r] = bv.x; Bs[kq * 4 + 1][r] = bv.y;
        Bs[kq * 4 + 2][r] = bv.z; Bs[kq * 4 + 3][r] = bv.w;
        __syncthreads();
#pragma unroll
        for (int kk = 0; kk < 16; ++kk) {
            float4 a = *(const float4*)&As[kk][tm * 4];
            float4 b = *(const float4*)&Bs[kk][tn * 4];
            float aa[4] = {a.x, a.y, a.z, a.w};
            float bb[4] = {b.x, b.y, b.z, b.w};
#pragma unroll
            for (int i = 0; i < 4; ++i)
#pragma unroll
                for (int j = 0; j < 4; ++j) acc[i][j] += aa[i] * bb[j];
        }
    }

#pragma unroll
    for (int i = 0; i < 4; ++i) {
        int gm = mb + tm * 4 + i;
        if (gm >= M) continue;
        float* crow;
        if (MODE == 0)
            crow = (gm < ng) ? (Gram + (size_t)gm * NGMAX) : (Dot + (size_t)(gm - ng) * NGMAX);
        else
            crow = Dotf + (size_t)gm * K_P;
#pragma unroll
        for (int j = 0; j < 4; ++j) {
            int gn = nb + tn * 4 + j;
            if (gn < N) crow[gn] = acc[i][j];
        }
    }
}

// -------- tiled sequential scan: 8-wave cooperative argmin (1 proto/lane) --------
__global__ __launch_bounds__(512, 1)
void k_scan_tiled(const float* __restrict__ Gram, const float* __restrict__ Dot,
                  const float* __restrict__ pn2_0, const float* __restrict__ zn2,
                  const int* __restrict__ gsteps, const int* __restrict__ scal,
                  int* __restrict__ winlist, int* __restrict__ clist,
                  int* __restrict__ cnt_out) {
    extern __shared__ char smem_raw[];
    float* sdot = (float*)smem_raw;             // [64][SDPITCH] transposed: sdot[x][k]
    float* sgram = sdot + 64 * SDPITCH;         // [64][65]
    float* szn2 = sgram + 64 * 65;              // [64]
    int* rowcnt = (int*)(szn2 + 64);            // [512] global win counts
    int* listlen = rowcnt + 512;                // [8]
    unsigned* scand = (unsigned*)(listlen + 8); // [2][16] parity-dbuf candidates

    int tid = threadIdx.x;
    int lane = tid & 63;
    int wave = tid >> 6;
    int ng = scal[0];

    rowcnt[tid] = 0;
    if (tid < 8) listlen[tid] = 0;
    float pn2 = pn2_0[tid];      // thread owns prototype k = tid
    __syncthreads();

    int ntiles = (ng + TILE - 1) / TILE;
    for (int T = 0; T < ntiles; ++T) {
        int j0 = T * TILE;
        int tlen = min(TILE, ng - j0);

        // ---- stage Dot0 tile (transposed) with mu^c scale fused ----
        {
            const float* basep = Dot + (size_t)(wave * 64) * NGMAX + j0 + lane;
            float* sb = sdot + lane * SDPITCH + wave * 64;
#pragma unroll 8
            for (int rr = 0; rr < 64; ++rr) {
                float sc = exp2f((float)rowcnt[wave * 64 + rr] * LOG2MU);
                sb[rr] = basep[(size_t)rr * NGMAX] * sc;
            }
        }
        // ---- corrections: wave streams its own flat list ----
        {
            int len = listlen[wave];
            const int* cl = clist + (size_t)wave * NGMAX;
            for (int i = 0; i < len; ++i) {
                int a = cl[i];
                int row = a & 511;
                int gq = (a >> 9) & 2047;
                int t = (a >> 20) & 4095;
                int c = rowcnt[row];
                float wq = OMU * exp2f((float)(c - 1 - gq) * LOG2MU);
                float gv = Gram[(size_t)t * NGMAX + j0 + lane];
                sdot[lane * SDPITCH + row] += wq * gv;
            }
        }
        // gram diag block + zn2
        {
            int t = tid >> 3, xo = (tid & 7) * 8;
            const float* src = Gram + (size_t)(j0 + t) * NGMAX + j0 + xo;
            float4 a = *(const float4*)(src);
            float4 b = *(const float4*)(src + 4);
            float* dst = sgram + t * 65 + xo;
            dst[0] = a.x; dst[1] = a.y; dst[2] = a.z; dst[3] = a.w;
            dst[4] = b.x; dst[5] = b.y; dst[6] = b.z; dst[7] = b.w;
        }
        if (tid < TILE) {
            szn2[tid] = (tid < tlen) ? zn2[gsteps[j0 + tid]] : 0.f;
        }
        __syncthreads();

        // ---- phase S: all 8 waves cooperate, 1 prototype per lane ----
        int c1 = (1 < tlen) ? 1 : 0;
        int c2 = (2 < tlen) ? 2 : (tlen - 1);
        float d_cur = sdot[tid];
        float d_nxt = sdot[c1 * SDPITCH + tid];
        float d_nn = sdot[c2 * SDPITCH + tid];
        float z2c = szn2[0];
        float g1c = sgram[1];
        float g2c = sgram[2];
        float g3c = sgram[3];
        int stw_reg = 0;

        for (int j = 0; j < tlen; ++j) {
            int par = (j & 1) << 4;
            const bool hn = (j + 1 < tlen);
            const bool h2 = (j + 2 < tlen);
            const bool h3 = (j + 3 < tlen);

            // phase 1: per-wave candidate
            float v = pn2 - 2.f * d_cur;
            float m = wave_min_f(v);
            unsigned long long bal = __ballot(v == m);
            int ll = (int)__builtin_ctzll(bal);
            unsigned bits = __float_as_uint(m);
            unsigned ou = bits ^ ((unsigned)(((int)bits) >> 31) | 0x80000000u);
            unsigned kk = (unsigned)((wave << 6) | ll);
            if (lane == 0) {
                scand[par + wave * 2] = kk;       // low word: index
                scand[par + wave * 2 + 1] = ou;   // high word: ordered value
            }
            // uniform scalar prefetches for next step (off critical path)
            int jn = hn ? (j + 1) : j;
            float z2n = szn2[jn];
            float g1n = sgram[jn * 65 + ((jn + 1 < 64) ? jn + 1 : 64)];
            float g2n = sgram[jn * 65 + ((jn + 2 < 64) ? jn + 2 : 64)];
            float g3n = sgram[jn * 65 + ((jn + 3 < 64) ? jn + 3 : 64)];
            // RMW gram operand prefetch
            int xr = j + 4 + lane;
            float grmw = sgram[j * 65 + ((xr < 64) ? xr : 64)];
            __syncthreads();

            // phase 2: all waves redundantly resolve global winner
            const unsigned long long* cb = (const unsigned long long*)(scand + par);
            unsigned long long k0 = cb[0], k1 = cb[1], k2 = cb[2], k3 = cb[3];
            unsigned long long k4 = cb[4], k5 = cb[5], k6 = cb[6], k7 = cb[7];
            unsigned long long a01 = (k1 < k0) ? k1 : k0;
            unsigned long long a23 = (k3 < k2) ? k3 : k2;
            unsigned long long a45 = (k5 < k4) ? k5 : k4;
            unsigned long long a67 = (k7 < k6) ? k7 : k6;
            unsigned long long a03 = (a23 < a01) ? a23 : a01;
            unsigned long long a47 = (a67 < a45) ? a67 : a45;
            unsigned long long aa = (a47 < a03) ? a47 : a03;
            int ks = (int)((unsigned)aa & 511u);

            if (wave == 0) stw_reg = (lane == j) ? ks : stw_reg;

            bool iswin = (tid == ks);
            if (iswin) {
                pn2 = MU * MU * pn2 + 2.f * MU * OMU * d_cur + OMU * OMU * z2c;
                if (hn) d_nxt = MU * d_nxt + OMU * g1c;
                if (h2) d_nn = MU * d_nn + OMU * g2c;
            }
            // prefetch col j+3 into pipeline
            int cp3 = h3 ? (j + 3) : (tlen - 1);
            float p3 = sdot[cp3 * SDPITCH + tid];
            if (iswin && h3) p3 = MU * p3 + OMU * g3c;
            // winner-row LDS update for cols >= j+4 (owner wave only)
            if ((ks >> 6) == wave && xr < tlen) {
                float* dp = sdot + xr * SDPITCH + ks;
                *dp = MU * *dp + OMU * grmw;
            }
            // shift pipeline
            d_cur = d_nxt; d_nxt = d_nn; d_nn = p3;
            z2c = z2n; g1c = g1n; g2c = g2n; g3c = g3n;
        }

        // ---- post-pass (wave 0): ranks, winlist append, per-wave correction lists ----
        if (wave == 0) {
            int wj = stw_reg;
            bool valid = (lane < tlen);
            int myL = wj >> 6;
            int rank = 0, mrow = 0, lpos = 0, lcnt = 0;
            for (int i = 0; i < tlen; ++i) {
                int wi = __builtin_amdgcn_readlane(wj, i);
                if (valid && wi == wj) {
                    mrow++;
                    if (i < lane) rank++;
                }
                if (valid && (wi >> 6) == myL) {
                    lcnt++;
                    if (i < lane) lpos++;
                }
            }
            bool first = valid && (rank == 0);
            bool firstL = valid && (lpos == 0);
            int base = rowcnt[wj];
            int lbase = listlen[myL];
            if (valid) {
                int gq = base + rank;
                winlist[(size_t)wj * NGMAX + gq] = j0 + lane;
                clist[(size_t)myL * NGMAX + lbase + lpos] =
                    wj | (gq << 9) | ((j0 + lane) << 20);
            }
            if (first) rowcnt[wj] += mrow;
            if (firstL) listlen[myL] += lcnt;
        }
        __syncthreads();
    }

    cnt_out[tid] = rowcnt[tid];
}

// -------- materialize final prototypes via win lists (block per prototype) --------
__global__ void k_mat(const float* __restrict__ Z, const float* __restrict__ P0,
                      const int* __restrict__ gsteps, const int* __restrict__ winlist,
                      const int* __restrict__ cnt, float* __restrict__ Pn) {
    int k = blockIdx.x;
    int tid = threadIdx.x;
    int c = cnt[k];
    float bw = exp2f((float)c * LOG2MU);
    const float4* p0r = (const float4*)(P0 + (size_t)k * D_F);
    float4 a0 = p0r[tid], a1 = p0r[tid + 256];
    a0.x *= bw; a0.y *= bw; a0.z *= bw; a0.w *= bw;
    a1.x *= bw; a1.y *= bw; a1.z *= bw; a1.w *= bw;
    const int* wl = winlist + (size_t)k * NGMAX;
    float w = OMU;
    for (int q = c - 1; q >= 0; --q) {
        int t = wl[q];
        const float4* zr = (const float4*)(Z + (size_t)gsteps[t] * D_F);
        float4 z0 = zr[tid], z1 = zr[tid + 256];
        a0.x += w * z0.x; a0.y += w * z0.y; a0.z += w * z0.z; a0.w += w * z0.w;
        a1.x += w * z1.x; a1.y += w * z1.y; a1.z += w * z1.z; a1.w += w * z1.w;
        w *= MU;
    }
    float4* pnr = (float4*)(Pn + (size_t)k * D_F);
    pnr[tid] = a0;
    pnr[tid + 256] = a1;
}

// -------- top-3 nearest + pull-loss row sums (wave per row) --------
__global__ void k_top3(const float* __restrict__ Dotf, const float* __restrict__ pn2f,
                       const float* __restrict__ Z, const float* __restrict__ Pn,
                       float* __restrict__ rowsum) {
    int row = blockIdx.x * 4 + (threadIdx.x >> 6);
    int lane = threadIdx.x & 63;
    float bv0 = FLTMAX, bv1 = FLTMAX, bv2 = FLTMAX;
    int bi0 = IMAX, bi1 = IMAX, bi2 = IMAX;
    for (int t = 0; t < 8; ++t) {
        int k = lane + 64 * t;
        float v = pn2f[k] - 2.f * Dotf[(size_t)row * K_P + k];
        if (argless(v, k, bv0, bi0)) {
            bv2 = bv1; bi2 = bi1; bv1 = bv0; bi1 = bi0; bv0 = v; bi0 = k;
        } else if (argless(v, k, bv1, bi1)) {
            bv2 = bv1; bi2 = bi1; bv1 = v; bi1 = k;
        } else if (argless(v, k, bv2, bi2)) {
            bv2 = v; bi2 = k;
        }
    }
    for (int off = 32; off; off >>= 1) {
        float a0 = bv0, a1 = bv1, a2 = bv2;
        int x0 = bi0, x1 = bi1, x2 = bi2;
        float b0 = __shfl_xor(bv0, off), b1 = __shfl_xor(bv1, off), b2 = __shfl_xor(bv2, off);
        int y0 = __shfl_xor(bi0, off), y1 = __shfl_xor(bi1, off), y2 = __shfl_xor(bi2, off);
        float nv[3]; int ni[3];
#pragma unroll
        for (int s = 0; s < 3; ++s) {
            bool ta = argless(a0, x0, b0, y0);
            nv[s] = ta ? a0 : b0;
            ni[s] = ta ? x0 : y0;
            if (ta) { a0 = a1; x0 = x1; a1 = a2; x1 = x2; a2 = FLTMAX; x2 = IMAX; }
            else    { b0 = b1; y0 = y1; b1 = b2; y1 = y2; b2 = FLTMAX; y2 = IMAX; }
        }
        bv0 = nv[0]; bv1 = nv[1]; bv2 = nv[2];
        bi0 = ni[0]; bi1 = ni[1]; bi2 = ni[2];
    }
    const float* pa = Pn + (size_t)bi0 * D_F;
    const float* pb = Pn + (size_t)bi1 * D_F;
    const float* pc = Pn + (size_t)bi2 * D_F;
    const float* zr = Z + (size_t)row * D_F;
    const float third = 1.f / 3.f;
    float acc = 0.f;
    for (int d0 = lane * 4; d0 < D_F; d0 += 256) {
        float4 z = *(const float4*)(zr + d0);
        float4 A = *(const float4*)(pa + d0);
        float4 Bv = *(const float4*)(pb + d0);
        float4 C = *(const float4*)(pc + d0);
        float m, df;
        m = (A.x + Bv.x + C.x) * third; df = z.x - m; acc += df * df;
        m = (A.y + Bv.y + C.y) * third; df = z.y - m; acc += df * df;
        m = (A.z + Bv.z + C.z) * third; df = z.z - m; acc += df * df;
        m = (A.w + Bv.w + C.w) * third; df = z.w - m; acc += df * df;
    }
    for (int off = 32; off; off >>= 1) acc += __shfl_xor(acc, off);
    if (lane == 0) rowsum[row] = acc;
}

// -------- push-loss row values (wave per row) --------
__global__ void k_push(const float* __restrict__ Z, const float* __restrict__ m_a_used,
                       const float* __restrict__ zn2, const float* __restrict__ scal_f,
                       float* __restrict__ rowpush) {
    int row = blockIdx.x * 4 + (threadIdx.x >> 6);
    int lane = threadIdx.x & 63;
    const float* zr = Z + (size_t)row * D_F;
    float acc = 0.f;
    for (int d0 = lane * 4; d0 < D_F; d0 += 256) {
        float4 z = *(const float4*)(zr + d0);
        float4 m = *(const float4*)(m_a_used + d0);
        acc += z.x * m.x + z.y * m.y + z.z * m.z + z.w * m.w;
    }
    for (int off = 32; off; off >>= 1) acc += __shfl_xor(acc, off);
    if (lane == 0) {
        float d2 = zn2[row] - 2.f * acc + scal_f[0];
        float dist = sqrtf(fmaxf(d2, 0.f));
        rowpush[row] = fmaxf(1.f - dist, 0.f);
    }
}

// -------- final combine --------
__global__ void k_final(const float* __restrict__ rowsum, const float* __restrict__ rowpush,
                        const int* __restrict__ scal, float* __restrict__ out) {
    __shared__ float red[1024];
    int tid = threadIdx.x;
    float s = 0.f;
    for (int i = tid; i < B_N; i += 1024) s += rowsum[i];
    red[tid] = s;
    __syncthreads();
    for (int off = 512; off; off >>= 1) {
        if (tid < off) red[tid] += red[tid + off];
        __syncthreads();
    }
    float pull = red[0] / ((float)B_N * (float)D_F);
    __syncthreads();
    float p = 0.f;
    for (int i = tid; i < B_N; i += 1024) p += rowpush[i];
    red[tid] = p;
    __syncthreads();
    for (int off = 512; off; off >>= 1) {
        if (tid < off) red[tid] += red[tid + off];
        __syncthreads();
    }
    if (tid == 0) {
        float lpush = (scal[1] > 0) ? (red[0] / (float)B_N) : 0.f;
        out[0] = pull + 0.5f * lpush;
    }
}

extern "C" void kernel_launch(void* const* d_in, const int* in_sizes, int n_in,
                              void* d_out, int out_size, void* d_ws, size_t ws_size,
                              hipStream_t stream) {
    const float* Z = (const float*)d_in[0];
    const int* g = (const int*)d_in[1];
    const float* P0 = (const float*)d_in[2];
    const float* ma_in = (const float*)d_in[4];
    float* out = (float*)d_out;

    float* ws = (float*)d_ws;
    float* Gram = ws;                                   // 16M floats
    float* Dotf = ws;                                   // overlaps Gram (Gram dead by then)
    float* Dot = ws + (size_t)NGMAX * NGMAX;            // 512*4096 (read-only after GEMM)
    float* Pn = Dot + (size_t)K_P * NGMAX;              // 512*2048
    float* zn2 = Pn + (size_t)K_P * D_F;                // 4096
    float* pn2_0 = zn2 + B_N;                           // 512
    float* pn2f = pn2_0 + K_P;                          // 512
    float* anom_part = pn2f + K_P;                      // 32*2048
    float* m_a_used = anom_part + 32 * D_F;             // 2048
    float* rowsum = m_a_used + D_F;                     // 4096
    float* rowpush = rowsum + B_N;                      // 4096
    float* scal_f = rowpush + B_N;                      // 16
    int* gsteps = (int*)(scal_f + 16);                  // 4096
    int* cnt = gsteps + B_N;                            // 512
    int* scal = cnt + K_P;                              // 16
    int* winlist = scal + 16;                           // 512*4096 (8 MB)
    int* clist = winlist + (size_t)K_P * NGMAX;         // 8*4096 (128 KB)

    hipFuncSetAttribute((const void*)k_scan_tiled,
                        hipFuncAttributeMaxDynamicSharedMemorySize, SMEM_BYTES);

    k_prep<<<1, 1024, 0, stream>>>(g, gsteps, scal);
    k_rownorm<<<(B_N + 3) / 4, 256, 0, stream>>>(Z, zn2, B_N);
    k_rownorm<<<(K_P + 3) / 4, 256, 0, stream>>>(P0, pn2_0, K_P);
    k_colsum<<<dim3(D_F / 256, 32), 256, 0, stream>>>(Z, g, anom_part);
    k_fin_ma<<<1, 1024, 0, stream>>>(anom_part, ma_in, scal, m_a_used, scal_f);
    k_gemm<0><<<dim3(NGMAX / 64, (NGMAX + K_P) / 64), 256, 0, stream>>>(
        Z, P0, Pn, gsteps, scal, Gram, Dot, Dotf);
    k_scan_tiled<<<1, 512, SMEM_BYTES, stream>>>(Gram, Dot, pn2_0, zn2, gsteps, scal,
                                                 winlist, clist, cnt);
    k_mat<<<K_P, 256, 0, stream>>>(Z, P0, gsteps, winlist, cnt, Pn);
    k_rownorm<<<(K_P + 3) / 4, 256, 0, stream>>>(Pn, pn2f, K_P);
    k_gemm<1><<<dim3(K_P / 64, B_N / 64), 256, 0, stream>>>(
        Z, P0, Pn, gsteps, scal, Gram, Dot, Dotf);
    k_top3<<<B_N / 4, 256, 0, stream>>>(Dotf, pn2f, Z, Pn, rowsum);
    k_push<<<B_N / 4, 256, 0, stream>>>(Z, m_a_used, zn2, scal_f, rowpush);
    k_final<<<1, 1024, 0, stream>>>(rowsum, rowpush, scal, out);
}

// Round 8
// 3090.317 us; speedup vs baseline: 1.1133x; 1.0391x over previous
//
#include <hip/hip_runtime.h>
#include <math.h>

#define B_N 4096
#define D_F 2048
#define K_P 512
#define NGMAX 4096
#define MU 0.9f
#define OMU (1.0f - MU)
#define LOG2MU (-0.15200309344504997f)
#define FLTMAX 3.402823466e+38f
#define IMAX 0x7FFFFFFF
#define TILE 64
#define SDPITCH 513

// LDS: scpk[128] u64 | sdot[64][513] | sgram[64][65] | szn2[64] | pn2_lds[512] | rowcnt[512] | listlen[8]
#define SMEM_BYTES (1024 + (64 * SDPITCH + 64 * 65 + 64 + 512) * 4 + (512 + 8) * 4)

__device__ __forceinline__ bool argless(float v1, int i1, float v2, int i2) {
    return (v1 < v2) || (v1 == v2 && i1 < i2);
}

__device__ __forceinline__ unsigned ford(float v) {
    unsigned b = __float_as_uint(v);
    return b ^ ((unsigned)(((int)b) >> 31) | 0x80000000u);
}

// DPP min-reduce: all lanes receive the wave min (via readlane 63).
template <int CTRL>
__device__ __forceinline__ float dppmin_f(float v) {
    int t = __builtin_amdgcn_update_dpp(__float_as_int(v), __float_as_int(v), CTRL, 0xf, 0xf, false);
    return fminf(v, __int_as_float(t));
}
__device__ __forceinline__ float wave_min_f(float v) {
    v = dppmin_f<0x111>(v);
    v = dppmin_f<0x112>(v);
    v = dppmin_f<0x114>(v);
    v = dppmin_f<0x118>(v);
    v = dppmin_f<0x142>(v);
    v = dppmin_f<0x143>(v);
    return __int_as_float(__builtin_amdgcn_readlane(__float_as_int(v), 63));
}

// -------- prep: compact gated indices, counts --------
__global__ void k_prep(const int* __restrict__ g, int* __restrict__ gsteps,
                       int* __restrict__ scal) {
    __shared__ int s[1024];
    __shared__ int base;
    int tid = threadIdx.x;
    if (tid == 0) base = 0;
    __syncthreads();
    for (int c = 0; c < 4; ++c) {
        int i = c * 1024 + tid;
        int gi = (g[i] != 0) ? 1 : 0;
        s[tid] = gi;
        __syncthreads();
        for (int off = 1; off < 1024; off <<= 1) {
            int v = (tid >= off) ? s[tid - off] : 0;
            __syncthreads();
            s[tid] += v;
            __syncthreads();
        }
        int pos = base + s[tid] - 1;
        if (gi) gsteps[pos] = i;
        __syncthreads();
        if (tid == 1023) base += s[1023];
        __syncthreads();
    }
    if (tid == 0) { scal[0] = base; scal[1] = B_N - base; }
}

// -------- row squared norms (wave per row) --------
__global__ void k_rownorm(const float* __restrict__ src, float* __restrict__ dst, int nrows) {
    int row = blockIdx.x * 4 + (threadIdx.x >> 6);
    int lane = threadIdx.x & 63;
    if (row >= nrows) return;
    const float* p = src + (size_t)row * D_F;
    float acc = 0.f;
    for (int d0 = lane * 4; d0 < D_F; d0 += 256) {
        float4 v = *(const float4*)(p + d0);
        acc += v.x * v.x + v.y * v.y + v.z * v.z + v.w * v.w;
    }
    for (int off = 32; off; off >>= 1) acc += __shfl_xor(acc, off);
    if (lane == 0) dst[row] = acc;
}

// -------- anomaly column sums (partials) --------
__global__ void k_colsum(const float* __restrict__ Z, const int* __restrict__ g,
                         float* __restrict__ anom_part) {
    int d = blockIdx.x * 256 + threadIdx.x;
    int rc = blockIdx.y;
    float acc = 0.f;
    int r0 = rc * 128;
    for (int r = r0; r < r0 + 128; ++r) {
        if (g[r] == 0) acc += Z[(size_t)r * D_F + d];
    }
    anom_part[(size_t)rc * D_F + d] = acc;
}

// -------- finalize m_a --------
__global__ void k_fin_ma(const float* __restrict__ anom_part, const float* __restrict__ ma_in,
                         const int* __restrict__ scal, float* __restrict__ m_a_used,
                         float* __restrict__ scal_f) {
    __shared__ float red[1024];
    int tid = threadIdx.x;
    int na = scal[1];
    float m2 = 0.f;
    for (int dd = tid; dd < D_F; dd += 1024) {
        float s = 0.f;
        for (int c = 0; c < 32; ++c) s += anom_part[(size_t)c * D_F + dd];
        float v = (na > 0) ? (s / (float)na) : ma_in[dd];
        m_a_used[dd] = v;
        m2 += v * v;
    }
    red[tid] = m2;
    __syncthreads();
    for (int off = 512; off; off >>= 1) {
        if (tid < off) red[tid] += red[tid + off];
        __syncthreads();
    }
    if (tid == 0) scal_f[0] = red[0];
}

// -------- GEMM (NT: C = A * B^T), 64x64 tile, BK=16, 256 thr, 4x4 micro --------
template <int MODE>
__global__ void k_gemm(const float* __restrict__ Z, const float* __restrict__ P0,
                       const float* __restrict__ Pn, const int* __restrict__ gsteps,
                       const int* __restrict__ scal, float* __restrict__ Gram,
                       float* __restrict__ Dot, float* __restrict__ Dotf) {
    int ng = scal[0];
    int M = (MODE == 0) ? (ng + K_P) : B_N;
    int N = (MODE == 0) ? ng : K_P;
    int mb = blockIdx.y * 64, nb = blockIdx.x * 64;
    if (mb >= M || nb >= N) return;
    if (MODE == 0 && (mb + 64 <= ng) && (nb + 64 <= mb)) return;

    __shared__ float As[16][68];
    __shared__ float Bs[16][68];
    __shared__ const float* rowA[64];
    __shared__ const float* rowB[64];

    int tid = threadIdx.x;
    if (tid < 64) {
        int gm = mb + tid;
        const float* pa = nullptr;
        if (MODE == 0) {
            if (gm < ng) pa = Z + (size_t)gsteps[gm] * D_F;
            else if (gm < ng + K_P) pa = P0 + (size_t)(gm - ng) * D_F;
        } else {
            if (gm < B_N) pa = Z + (size_t)gm * D_F;
        }
        rowA[tid] = pa;
    } else if (tid < 128) {
        int t = tid - 64;
        int gn = nb + t;
        const float* pb = nullptr;
        if (MODE == 0) { if (gn < ng) pb = Z + (size_t)gsteps[gn] * D_F; }
        else { if (gn < K_P) pb = Pn + (size_t)gn * D_F; }
        rowB[t] = pb;
    }
    __syncthreads();

    int r = tid & 63, kq = tid >> 6;
    int tm = tid >> 4, tn = tid & 15;
    const float* pa = rowA[r];
    const float* pb = rowB[r];

    float acc[4][4] = {};
    for (int k0 = 0; k0 < D_F; k0 += 16) {
        float4 av = pa ? *(const float4*)(pa + k0 + kq * 4) : make_float4(0.f, 0.f, 0.f, 0.f);
        float4 bv = pb ? *(const float4*)(pb + k0 + kq * 4) : make_float4(0.f, 0.f, 0.f, 0.f);
        __syncthreads();
        As[kq * 4 + 0][r] = av.x; As[kq * 4 + 1][r] = av.y;
        As[kq * 4 + 2][r] = av.z; As[kq * 4 + 3][r] = av.w;
        Bs[kq * 4 + 0][r] = bv.x; Bs[kq * 4 + 1][r] = bv.y;
        Bs[kq * 4 + 2][r] = bv.z; Bs[kq * 4 + 3][r] = bv.w;
        __syncthreads();
#pragma unroll
        for (int kk = 0; kk < 16; ++kk) {
            float4 a = *(const float4*)&As[kk][tm * 4];
            float4 b = *(const float4*)&Bs[kk][tn * 4];
            float aa[4] = {a.x, a.y, a.z, a.w};
            float bb[4] = {b.x, b.y, b.z, b.w};
#pragma unroll
            for (int i = 0; i < 4; ++i)
#pragma unroll
                for (int j = 0; j < 4; ++j) acc[i][j] += aa[i] * bb[j];
        }
    }

#pragma unroll
    for (int i = 0; i < 4; ++i) {
        int gm = mb + tm * 4 + i;
        if (gm >= M) continue;
        float* crow;
        if (MODE == 0)
            crow = (gm < ng) ? (Gram + (size_t)gm * NGMAX) : (Dot + (size_t)(gm - ng) * NGMAX);
        else
            crow = Dotf + (size_t)gm * K_P;
#pragma unroll
        for (int j = 0; j < 4; ++j) {
            int gn = nb + tn * 4 + j;
            if (gn < N) crow[gn] = acc[i][j];
        }
    }
}

// -------- tiled sequential scan: clean/dirty split, wave-0 hot loop, no barriers --------
__global__ __launch_bounds__(512, 1)
void k_scan_tiled(const float* __restrict__ Gram, const float* __restrict__ Dot,
                  const float* __restrict__ pn2_0, const float* __restrict__ zn2,
                  const int* __restrict__ gsteps, const int* __restrict__ scal,
                  int* __restrict__ winlist, int* __restrict__ clist,
                  int* __restrict__ cnt_out) {
    extern __shared__ char smem_raw[];
    unsigned long long* scpk = (unsigned long long*)smem_raw;  // [128]: top1 [0..63], top2 [64..127]
    float* sdot = (float*)(scpk + 128);        // [64][SDPITCH] transposed: sdot[x][k]
    float* sgram = sdot + 64 * SDPITCH;        // [64][65]
    float* szn2 = sgram + 64 * 65;             // [64]
    float* pn2_lds = szn2 + 64;                // [512] current ||p_k||^2
    int* rowcnt = (int*)(pn2_lds + 512);       // [512] global win counts
    int* listlen = rowcnt + 512;               // [8]

    int tid = threadIdx.x;
    int lane = tid & 63;
    int wave = tid >> 6;
    int ng = scal[0];

    rowcnt[tid] = 0;
    if (tid < 8) listlen[tid] = 0;
    pn2_lds[tid] = pn2_0[tid];
    __syncthreads();

    int ntiles = (ng + TILE - 1) / TILE;
    for (int T = 0; T < ntiles; ++T) {
        int j0 = T * TILE;
        int tlen = min(TILE, ng - j0);

        // ---- stage Dot0 tile (transposed) with mu^c scale fused ----
        {
            const float* basep = Dot + (size_t)(wave * 64) * NGMAX + j0 + lane;
            float* sb = sdot + lane * SDPITCH + wave * 64;
#pragma unroll 8
            for (int rr = 0; rr < 64; ++rr) {
                float sc = exp2f((float)rowcnt[wave * 64 + rr] * LOG2MU);
                sb[rr] = basep[(size_t)rr * NGMAX] * sc;
            }
        }
        // ---- corrections: wave streams its own flat list ----
        {
            int len = listlen[wave];
            const int* cl = clist + (size_t)wave * NGMAX;
            for (int i = 0; i < len; ++i) {
                int a = cl[i];
                int row = a & 511;
                int gq = (a >> 9) & 2047;
                int t = (a >> 20) & 4095;
                int c = rowcnt[row];
                float wq = OMU * exp2f((float)(c - 1 - gq) * LOG2MU);
                float gv = Gram[(size_t)t * NGMAX + j0 + lane];
                sdot[lane * SDPITCH + row] += wq * gv;
            }
        }
        // gram diag block + zn2
        {
            int t = tid >> 3, xo = (tid & 7) * 8;
            const float* src = Gram + (size_t)(j0 + t) * NGMAX + j0 + xo;
            float4 a = *(const float4*)(src);
            float4 b = *(const float4*)(src + 4);
            float* dst = sgram + t * 65 + xo;
            dst[0] = a.x; dst[1] = a.y; dst[2] = a.z; dst[3] = a.w;
            dst[4] = b.x; dst[5] = b.y; dst[6] = b.z; dst[7] = b.w;
        }
        if (tid < TILE) {
            szn2[tid] = (tid < tlen) ? zn2[gsteps[j0 + tid]] : 0.f;
        }
        __syncthreads();

        // ---- precompute: per-column top-2 clean candidates (all 8 waves, 8 cols each) ----
        {
#pragma unroll
            for (int q = 0; q < 8; ++q) {
                int c = wave * 8 + q;
                unsigned long long m1 = 0xFFFFFFFFFFFFFFFFull, m2 = 0xFFFFFFFFFFFFFFFFull;
                const float* col = sdot + c * SDPITCH;
#pragma unroll
                for (int t = 0; t < 8; ++t) {
                    int k = t * 64 + lane;
                    float v = pn2_lds[k] - 2.f * col[k];
                    unsigned long long pk = ((unsigned long long)ford(v) << 9) | (unsigned)k;
                    if (pk < m1) { m2 = m1; m1 = pk; }
                    else if (pk < m2) { m2 = pk; }
                }
#pragma unroll
                for (int off = 32; off; off >>= 1) {
                    unsigned long long b1 = __shfl_xor(m1, off);
                    unsigned long long b2 = __shfl_xor(m2, off);
                    unsigned long long lo = (m1 < b1) ? m1 : b1;
                    unsigned long long hi = (m1 < b1) ? b1 : m1;
                    unsigned long long s2 = (m2 < b2) ? m2 : b2;
                    m1 = lo;
                    m2 = (hi < s2) ? hi : s2;
                }
                if (lane == 0) { scpk[c] = m1; scpk[64 + c] = m2; }
            }
        }
        __syncthreads();

        // ---- phase S (wave 0 only): dirty/clean resolution, no barriers ----
        if (wave == 0) {
            int k_d = 0; float pn2_d = 0.f, dotj = 0.f;
            unsigned dmask = 0;
            int ndirty = 0;
            int stw_reg = 0;
            unsigned long long c1 = scpk[0], c2 = scpk[64];
            float z2c = szn2[0];
            int xi0 = 1 + lane;
            float grmw = sgram[(xi0 <= 64) ? xi0 : 64];

            for (int j = 0; j < tlen; ++j) {
                bool active = (lane < ndirty);
                float dval = FLTMAX;
                if (active) {
                    dotj = sdot[j * SDPITCH + k_d];
                    dval = pn2_d - 2.f * dotj;
                }
                // prefetch next-step uniforms
                int jn = (j + 1 < tlen) ? (j + 1) : j;
                unsigned long long c1n = scpk[jn], c2n = scpk[64 + jn];
                float z2n = szn2[jn];
                int xrn = jn + 1 + lane;
                float grmw_n = sgram[jn * 65 + ((xrn <= 64) ? xrn : 64)];

                int ks;
                float mdv = FLTMAX; int mdk = 511;
                if (ndirty > 0) {
                    float m = wave_min_f(dval);
                    unsigned long long bal = __ballot(active && (dval == m));
                    int kk = 511;
                    do {
                        int l = (int)__builtin_ctzll(bal);
                        bal &= bal - 1;
                        int kr = __builtin_amdgcn_readlane(k_d, l);
                        kk = min(kk, kr);
                    } while (bal);
                    mdv = m; mdk = kk;
                }
                int i1 = (int)(c1 & 511u), i2 = (int)(c2 & 511u);
                unsigned fl1 = (__builtin_amdgcn_readlane(dmask, i1 >> 3) >> (i1 & 7)) & 1u;
                unsigned fl2 = (__builtin_amdgcn_readlane(dmask, i2 >> 3) >> (i2 & 7)) & 1u;
                if (fl1 & fl2) {
                    // fallback: exact argmin over all 512 (sdot + pn2_lds are current)
                    unsigned long long pk = 0xFFFFFFFFFFFFFFFFull;
#pragma unroll
                    for (int t = 0; t < 8; ++t) {
                        int k = t * 64 + lane;
                        float v = pn2_lds[k] - 2.f * sdot[j * SDPITCH + k];
                        unsigned long long p = ((unsigned long long)ford(v) << 9) | (unsigned)k;
                        pk = (p < pk) ? p : pk;
                    }
#pragma unroll
                    for (int off = 32; off; off >>= 1) {
                        unsigned long long o = __shfl_xor(pk, off);
                        pk = (o < pk) ? o : pk;
                    }
                    ks = (int)(pk & 511u);
                } else {
                    unsigned long long cc = fl1 ? c2 : c1;
                    if (ndirty > 0) {
                        unsigned long long pkd =
                            ((unsigned long long)ford(mdv) << 9) | (unsigned)mdk;
                        cc = (pkd < cc) ? pkd : cc;
                    }
                    ks = (int)(cc & 511u);
                }
                stw_reg = (lane == j) ? ks : stw_reg;

                unsigned wasdirty = (__builtin_amdgcn_readlane(dmask, ks >> 3) >> (ks & 7)) & 1u;
                if (lane == (ks >> 3)) dmask |= (1u << (ks & 7));
                if (wasdirty) {
                    if (active && k_d == ks) {
                        pn2_d = MU * MU * pn2_d + 2.f * MU * OMU * dotj + OMU * OMU * z2c;
                        pn2_lds[ks] = pn2_d;
                    }
                } else {
                    if (lane == ndirty) {
                        k_d = ks;
                        float dd = sdot[j * SDPITCH + ks];
                        float p0v = pn2_lds[ks];
                        pn2_d = MU * MU * p0v + 2.f * MU * OMU * dd + OMU * OMU * z2c;
                        pn2_lds[ks] = pn2_d;
                    }
                    ndirty += 1;
                }
                // winner-row RMW for all future in-tile columns (keeps dirty rows current)
                int x = j + 1 + lane;
                if (x < tlen) {
                    float* dp = sdot + x * SDPITCH + ks;
                    *dp = MU * *dp + OMU * grmw;
                }
                c1 = c1n; c2 = c2n; z2c = z2n; grmw = grmw_n;
            }

            // ---- post-pass: ranks, winlist append, per-wave correction lists ----
            int wj = stw_reg;
            bool valid = (lane < tlen);
            int myL = wj >> 6;
            int rank = 0, mrow = 0, lpos = 0, lcnt = 0;
            for (int i = 0; i < tlen; ++i) {
                int wi = __builtin_amdgcn_readlane(wj, i);
                if (valid && wi == wj) {
                    mrow++;
                    if (i < lane) rank++;
                }
                if (valid && (wi >> 6) == myL) {
                    lcnt++;
                    if (i < lane) lpos++;
                }
            }
            bool first = valid && (rank == 0);
            bool firstL = valid && (lpos == 0);
            int base = rowcnt[wj];
            int lbase = listlen[myL];
            if (valid) {
                int gq = base + rank;
                winlist[(size_t)wj * NGMAX + gq] = j0 + lane;
                clist[(size_t)myL * NGMAX + lbase + lpos] =
                    wj | (gq << 9) | ((j0 + lane) << 20);
            }
            if (first) rowcnt[wj] += mrow;
            if (firstL) listlen[myL] += lcnt;
        }
        __syncthreads();
    }

    cnt_out[tid] = rowcnt[tid];
}

// -------- materialize final prototypes via win lists (block per prototype) --------
__global__ void k_mat(const float* __restrict__ Z, const float* __restrict__ P0,
                      const int* __restrict__ gsteps, const int* __restrict__ winlist,
                      const int* __restrict__ cnt, float* __restrict__ Pn) {
    int k = blockIdx.x;
    int tid = threadIdx.x;
    int c = cnt[k];
    float bw = exp2f((float)c * LOG2MU);
    const float4* p0r = (const float4*)(P0 + (size_t)k * D_F);
    float4 a0 = p0r[tid], a1 = p0r[tid + 256];
    a0.x *= bw; a0.y *= bw; a0.z *= bw; a0.w *= bw;
    a1.x *= bw; a1.y *= bw; a1.z *= bw; a1.w *= bw;
    const int* wl = winlist + (size_t)k * NGMAX;
    float w = OMU;
    for (int q = c - 1; q >= 0; --q) {
        int t = wl[q];
        const float4* zr = (const float4*)(Z + (size_t)gsteps[t] * D_F);
        float4 z0 = zr[tid], z1 = zr[tid + 256];
        a0.x += w * z0.x; a0.y += w * z0.y; a0.z += w * z0.z; a0.w += w * z0.w;
        a1.x += w * z1.x; a1.y += w * z1.y; a1.z += w * z1.z; a1.w += w * z1.w;
        w *= MU;
    }
    float4* pnr = (float4*)(Pn + (size_t)k * D_F);
    pnr[tid] = a0;
    pnr[tid + 256] = a1;
}

// -------- top-3 nearest + pull-loss row sums (wave per row) --------
__global__ void k_top3(const float* __restrict__ Dotf, const float* __restrict__ pn2f,
                       const float* __restrict__ Z, const float* __restrict__ Pn,
                       float* __restrict__ rowsum) {
    int row = blockIdx.x * 4 + (threadIdx.x >> 6);
    int lane = threadIdx.x & 63;
    float bv0 = FLTMAX, bv1 = FLTMAX, bv2 = FLTMAX;
    int bi0 = IMAX, bi1 = IMAX, bi2 = IMAX;
    for (int t = 0; t < 8; ++t) {
        int k = lane + 64 * t;
        float v = pn2f[k] - 2.f * Dotf[(size_t)row * K_P + k];
        if (argless(v, k, bv0, bi0)) {
            bv2 = bv1; bi2 = bi1; bv1 = bv0; bi1 = bi0; bv0 = v; bi0 = k;
        } else if (argless(v, k, bv1, bi1)) {
            bv2 = bv1; bi2 = bi1; bv1 = v; bi1 = k;
        } else if (argless(v, k, bv2, bi2)) {
            bv2 = v; bi2 = k;
        }
    }
    for (int off = 32; off; off >>= 1) {
        float a0 = bv0, a1 = bv1, a2 = bv2;
        int x0 = bi0, x1 = bi1, x2 = bi2;
        float b0 = __shfl_xor(bv0, off), b1 = __shfl_xor(bv1, off), b2 = __shfl_xor(bv2, off);
        int y0 = __shfl_xor(bi0, off), y1 = __shfl_xor(bi1, off), y2 = __shfl_xor(bi2, off);
        float nv[3]; int ni[3];
#pragma unroll
        for (int s = 0; s < 3; ++s) {
            bool ta = argless(a0, x0, b0, y0);
            nv[s] = ta ? a0 : b0;
            ni[s] = ta ? x0 : y0;
            if (ta) { a0 = a1; x0 = x1; a1 = a2; x1 = x2; a2 = FLTMAX; x2 = IMAX; }
            else    { b0 = b1; y0 = y1; b1 = b2; y1 = y2; b2 = FLTMAX; y2 = IMAX; }
        }
        bv0 = nv[0]; bv1 = nv[1]; bv2 = nv[2];
        bi0 = ni[0]; bi1 = ni[1]; bi2 = ni[2];
    }
    const float* pa = Pn + (size_t)bi0 * D_F;
    const float* pb = Pn + (size_t)bi1 * D_F;
    const float* pc = Pn + (size_t)bi2 * D_F;
    const float* zr = Z + (size_t)row * D_F;
    const float third = 1.f / 3.f;
    float acc = 0.f;
    for (int d0 = lane * 4; d0 < D_F; d0 += 256) {
        float4 z = *(const float4*)(zr + d0);
        float4 A = *(const float4*)(pa + d0);
        float4 Bv = *(const float4*)(pb + d0);
        float4 C = *(const float4*)(pc + d0);
        float m, df;
        m = (A.x + Bv.x + C.x) * third; df = z.x - m; acc += df * df;
        m = (A.y + Bv.y + C.y) * third; df = z.y - m; acc += df * df;
        m = (A.z + Bv.z + C.z) * third; df = z.z - m; acc += df * df;
        m = (A.w + Bv.w + C.w) * third; df = z.w - m; acc += df * df;
    }
    for (int off = 32; off; off >>= 1) acc += __shfl_xor(acc, off);
    if (lane == 0) rowsum[row] = acc;
}

// -------- push-loss row values (wave per row) --------
__global__ void k_push(const float* __restrict__ Z, const float* __restrict__ m_a_used,
                       const float* __restrict__ zn2, const float* __restrict__ scal_f,
                       float* __restrict__ rowpush) {
    int row = blockIdx.x * 4 + (threadIdx.x >> 6);
    int lane = threadIdx.x & 63;
    const float* zr = Z + (size_t)row * D_F;
    float acc = 0.f;
    for (int d0 = lane * 4; d0 < D_F; d0 += 256) {
        float4 z = *(const float4*)(zr + d0);
        float4 m = *(const float4*)(m_a_used + d0);
        acc += z.x * m.x + z.y * m.y + z.z * m.z + z.w * m.w;
    }
    for (int off = 32; off; off >>= 1) acc += __shfl_xor(acc, off);
    if (lane == 0) {
        float d2 = zn2[row] - 2.f * acc + scal_f[0];
        float dist = sqrtf(fmaxf(d2, 0.f));
        rowpush[row] = fmaxf(1.f - dist, 0.f);
    }
}

// -------- final combine --------
__global__ void k_final(const float* __restrict__ rowsum, const float* __restrict__ rowpush,
                        const int* __restrict__ scal, float* __restrict__ out) {
    __shared__ float red[1024];
    int tid = threadIdx.x;
    float s = 0.f;
    for (int i = tid; i < B_N; i += 1024) s += rowsum[i];
    red[tid] = s;
    __syncthreads();
    for (int off = 512; off; off >>= 1) {
        if (tid < off) red[tid] += red[tid + off];
        __syncthreads();
    }
    float pull = red[0] / ((float)B_N * (float)D_F);
    __syncthreads();
    float p = 0.f;
    for (int i = tid; i < B_N; i += 1024) p += rowpush[i];
    red[tid] = p;
    __syncthreads();
    for (int off = 512; off; off >>= 1) {
        if (tid < off) red[tid] += red[tid + off];
        __syncthreads();
    }
    if (tid == 0) {
        float lpush = (scal[1] > 0) ? (red[0] / (float)B_N) : 0.f;
        out[0] = pull + 0.5f * lpush;
    }
}

extern "C" void kernel_launch(void* const* d_in, const int* in_sizes, int n_in,
                              void* d_out, int out_size, void* d_ws, size_t ws_size,
                              hipStream_t stream) {
    const float* Z = (const float*)d_in[0];
    const int* g = (const int*)d_in[1];
    const float* P0 = (const float*)d_in[2];
    const float* ma_in = (const float*)d_in[4];
    float* out = (float*)d_out;

    float* ws = (float*)d_ws;
    float* Gram = ws;                                   // 16M floats
    float* Dotf = ws;                                   // overlaps Gram (Gram dead by then)
    float* Dot = ws + (size_t)NGMAX * NGMAX;            // 512*4096 (read-only after GEMM)
    float* Pn = Dot + (size_t)K_P * NGMAX;              // 512*2048
    float* zn2 = Pn + (size_t)K_P * D_F;                // 4096
    float* pn2_0 = zn2 + B_N;                           // 512
    float* pn2f = pn2_0 + K_P;                          // 512
    float* anom_part = pn2f + K_P;                      // 32*2048
    float* m_a_used = anom_part + 32 * D_F;             // 2048
    float* rowsum = m_a_used + D_F;                     // 4096
    float* rowpush = rowsum + B_N;                      // 4096
    float* scal_f = rowpush + B_N;                      // 16
    int* gsteps = (int*)(scal_f + 16);                  // 4096
    int* cnt = gsteps + B_N;                            // 512
    int* scal = cnt + K_P;                              // 16
    int* winlist = scal + 16;                           // 512*4096 (8 MB)
    int* clist = winlist + (size_t)K_P * NGMAX;         // 8*4096 (128 KB)

    hipFuncSetAttribute((const void*)k_scan_tiled,
                        hipFuncAttributeMaxDynamicSharedMemorySize, SMEM_BYTES);

    k_prep<<<1, 1024, 0, stream>>>(g, gsteps, scal);
    k_rownorm<<<(B_N + 3) / 4, 256, 0, stream>>>(Z, zn2, B_N);
    k_rownorm<<<(K_P + 3) / 4, 256, 0, stream>>>(P0, pn2_0, K_P);
    k_colsum<<<dim3(D_F / 256, 32), 256, 0, stream>>>(Z, g, anom_part);
    k_fin_ma<<<1, 1024, 0, stream>>>(anom_part, ma_in, scal, m_a_used, scal_f);
    k_gemm<0><<<dim3(NGMAX / 64, (NGMAX + K_P) / 64), 256, 0, stream>>>(
        Z, P0, Pn, gsteps, scal, Gram, Dot, Dotf);
    k_scan_tiled<<<1, 512, SMEM_BYTES, stream>>>(Gram, Dot, pn2_0, zn2, gsteps, scal,
                                                 winlist, clist, cnt);
    k_mat<<<K_P, 256, 0, stream>>>(Z, P0, gsteps, winlist, cnt, Pn);
    k_rownorm<<<(K_P + 3) / 4, 256, 0, stream>>>(Pn, pn2f, K_P);
    k_gemm<1><<<dim3(K_P / 64, B_N / 64), 256, 0, stream>>>(
        Z, P0, Pn, gsteps, scal, Gram, Dot, Dotf);
    k_top3<<<B_N / 4, 256, 0, stream>>>(Dotf, pn2f, Z, Pn, rowsum);
    k_push<<<B_N / 4, 256, 0, stream>>>(Z, m_a_used, zn2, scal_f, rowpush);
    k_final<<<1, 1024, 0, stream>>>(rowsum, rowpush, scal, out);
}

// Round 9
// 2605.032 us; speedup vs baseline: 1.3207x; 1.1863x over previous
//
#include <hip/hip_runtime.h>
#include <math.h>

#define B_N 4096
#define D_F 2048
#define K_P 512
#define NGMAX 4096
#define MU 0.9f
#define OMU (1.0f - MU)
#define LOG2MU (-0.15200309344504997f)
#define FLTMAX 3.402823466e+38f
#define IMAX 0x7FFFFFFF
#define TILE 64
#define SDPITCH 513

// LDS carve (floats/ints)
#define SMEM_FLOATS (64 * SDPITCH + 64 * 65 + 64)
#define SMEM_INTS (512 + 16)
#define SMEM_BYTES ((SMEM_FLOATS + SMEM_INTS) * 4)

__device__ __forceinline__ bool argless(float v1, int i1, float v2, int i2) {
    return (v1 < v2) || (v1 == v2 && i1 < i2);
}

// u32 DPP min-reduce: lane 63 holds the wave min; readlane broadcasts.
template <int CTRL>
__device__ __forceinline__ unsigned dppmin_u(unsigned v) {
    unsigned t = (unsigned)__builtin_amdgcn_update_dpp((int)v, (int)v, CTRL, 0xf, 0xf, false);
    return min(v, t);
}
__device__ __forceinline__ unsigned wave_min_u(unsigned v) {
    v = dppmin_u<0x111>(v);  // row_shr:1
    v = dppmin_u<0x112>(v);  // row_shr:2
    v = dppmin_u<0x114>(v);  // row_shr:4
    v = dppmin_u<0x118>(v);  // row_shr:8
    v = dppmin_u<0x142>(v);  // row_bcast:15
    v = dppmin_u<0x143>(v);  // row_bcast:31
    return (unsigned)__builtin_amdgcn_readlane((int)v, 63);
}

// -------- prep: compact gated indices, counts --------
__global__ void k_prep(const int* __restrict__ g, int* __restrict__ gsteps,
                       int* __restrict__ scal) {
    __shared__ int s[1024];
    __shared__ int base;
    int tid = threadIdx.x;
    if (tid == 0) base = 0;
    __syncthreads();
    for (int c = 0; c < 4; ++c) {
        int i = c * 1024 + tid;
        int gi = (g[i] != 0) ? 1 : 0;
        s[tid] = gi;
        __syncthreads();
        for (int off = 1; off < 1024; off <<= 1) {
            int v = (tid >= off) ? s[tid - off] : 0;
            __syncthreads();
            s[tid] += v;
            __syncthreads();
        }
        int pos = base + s[tid] - 1;
        if (gi) gsteps[pos] = i;
        __syncthreads();
        if (tid == 1023) base += s[1023];
        __syncthreads();
    }
    if (tid == 0) { scal[0] = base; scal[1] = B_N - base; }
}

// -------- row squared norms (wave per row) --------
__global__ void k_rownorm(const float* __restrict__ src, float* __restrict__ dst, int nrows) {
    int row = blockIdx.x * 4 + (threadIdx.x >> 6);
    int lane = threadIdx.x & 63;
    if (row >= nrows) return;
    const float* p = src + (size_t)row * D_F;
    float acc = 0.f;
    for (int d0 = lane * 4; d0 < D_F; d0 += 256) {
        float4 v = *(const float4*)(p + d0);
        acc += v.x * v.x + v.y * v.y + v.z * v.z + v.w * v.w;
    }
    for (int off = 32; off; off >>= 1) acc += __shfl_xor(acc, off);
    if (lane == 0) dst[row] = acc;
}

// -------- anomaly column sums (partials) --------
__global__ void k_colsum(const float* __restrict__ Z, const int* __restrict__ g,
                         float* __restrict__ anom_part) {
    int d = blockIdx.x * 256 + threadIdx.x;
    int rc = blockIdx.y;
    float acc = 0.f;
    int r0 = rc * 128;
    for (int r = r0; r < r0 + 128; ++r) {
        if (g[r] == 0) acc += Z[(size_t)r * D_F + d];
    }
    anom_part[(size_t)rc * D_F + d] = acc;
}

// -------- finalize m_a --------
__global__ void k_fin_ma(const float* __restrict__ anom_part, const float* __restrict__ ma_in,
                         const int* __restrict__ scal, float* __restrict__ m_a_used,
                         float* __restrict__ scal_f) {
    __shared__ float red[1024];
    int tid = threadIdx.x;
    int na = scal[1];
    float m2 = 0.f;
    for (int dd = tid; dd < D_F; dd += 1024) {
        float s = 0.f;
        for (int c = 0; c < 32; ++c) s += anom_part[(size_t)c * D_F + dd];
        float v = (na > 0) ? (s / (float)na) : ma_in[dd];
        m_a_used[dd] = v;
        m2 += v * v;
    }
    red[tid] = m2;
    __syncthreads();
    for (int off = 512; off; off >>= 1) {
        if (tid < off) red[tid] += red[tid + off];
        __syncthreads();
    }
    if (tid == 0) scal_f[0] = red[0];
}

// -------- GEMM (NT: C = A * B^T), 64x64 tile, BK=16, 256 thr, 4x4 micro --------
template <int MODE>
__global__ void k_gemm(const float* __restrict__ Z, const float* __restrict__ P0,
                       const float* __restrict__ Pn, const int* __restrict__ gsteps,
                       const int* __restrict__ scal, float* __restrict__ Gram,
                       float* __restrict__ Dot, float* __restrict__ Dotf) {
    int ng = scal[0];
    int M = (MODE == 0) ? (ng + K_P) : B_N;
    int N = (MODE == 0) ? ng : K_P;
    int mb = blockIdx.y * 64, nb = blockIdx.x * 64;
    if (mb >= M || nb >= N) return;
    if (MODE == 0 && (mb + 64 <= ng) && (nb + 64 <= mb)) return;

    __shared__ float As[16][68];
    __shared__ float Bs[16][68];
    __shared__ const float* rowA[64];
    __shared__ const float* rowB[64];

    int tid = threadIdx.x;
    if (tid < 64) {
        int gm = mb + tid;
        const float* pa = nullptr;
        if (MODE == 0) {
            if (gm < ng) pa = Z + (size_t)gsteps[gm] * D_F;
            else if (gm < ng + K_P) pa = P0 + (size_t)(gm - ng) * D_F;
        } else {
            if (gm < B_N) pa = Z + (size_t)gm * D_F;
        }
        rowA[tid] = pa;
    } else if (tid < 128) {
        int t = tid - 64;
        int gn = nb + t;
        const float* pb = nullptr;
        if (MODE == 0) { if (gn < ng) pb = Z + (size_t)gsteps[gn] * D_F; }
        else { if (gn < K_P) pb = Pn + (size_t)gn * D_F; }
        rowB[t] = pb;
    }
    __syncthreads();

    int r = tid & 63, kq = tid >> 6;
    int tm = tid >> 4, tn = tid & 15;
    const float* pa = rowA[r];
    const float* pb = rowB[r];

    float acc[4][4] = {};
    for (int k0 = 0; k0 < D_F; k0 += 16) {
        float4 av = pa ? *(const float4*)(pa + k0 + kq * 4) : make_float4(0.f, 0.f, 0.f, 0.f);
        float4 bv = pb ? *(const float4*)(pb + k0 + kq * 4) : make_float4(0.f, 0.f, 0.f, 0.f);
        __syncthreads();
        As[kq * 4 + 0][r] = av.x; As[kq * 4 + 1][r] = av.y;
        As[kq * 4 + 2][r] = av.z; As[kq * 4 + 3][r] = av.w;
        Bs[kq * 4 + 0][r] = bv.x; Bs[kq * 4 + 1][r] = bv.y;
        Bs[kq * 4 + 2][r] = bv.z; Bs[kq * 4 + 3][r] = bv.w;
        __syncthreads();
#pragma unroll
        for (int kk = 0; kk < 16; ++kk) {
            float4 a = *(const float4*)&As[kk][tm * 4];
            float4 b = *(const float4*)&Bs[kk][tn * 4];
            float aa[4] = {a.x, a.y, a.z, a.w};
            float bb[4] = {b.x, b.y, b.z, b.w};
#pragma unroll
            for (int i = 0; i < 4; ++i)
#pragma unroll
                for (int j = 0; j < 4; ++j) acc[i][j] += aa[i] * bb[j];
        }
    }

#pragma unroll
    for (int i = 0; i < 4; ++i) {
        int gm = mb + tm * 4 + i;
        if (gm >= M) continue;
        float* crow;
        if (MODE == 0)
            crow = (gm < ng) ? (Gram + (size_t)gm * NGMAX) : (Dot + (size_t)(gm - ng) * NGMAX);
        else
            crow = Dotf + (size_t)gm * K_P;
#pragma unroll
        for (int j = 0; j < 4; ++j) {
            int gn = nb + tn * 4 + j;
            if (gn < N) crow[gn] = acc[i][j];
        }
    }
}

// -------- tiled sequential scan: packed-key single-chain argmin (R5 structure) --------
__global__ __launch_bounds__(512, 1)
void k_scan_tiled(const float* __restrict__ Gram, const float* __restrict__ Dot,
                  const float* __restrict__ pn2_0, const float* __restrict__ zn2,
                  const int* __restrict__ gsteps, const int* __restrict__ scal,
                  int* __restrict__ winlist, int* __restrict__ clist,
                  int* __restrict__ cnt_out) {
    extern __shared__ char smem_raw[];
    float* sdot = (float*)smem_raw;             // [64][SDPITCH] transposed: sdot[x][k]
    float* sgram = sdot + 64 * SDPITCH;         // [64][65]
    float* szn2 = sgram + 64 * 65;              // [64]
    int* rowcnt = (int*)(szn2 + 64);            // [512] global win counts
    int* listlen = rowcnt + 512;                // [8] per-wave correction-list lengths

    int tid = threadIdx.x;
    int lane = tid & 63;
    int wave = tid >> 6;
    int ng = scal[0];

    rowcnt[tid] = 0;
    if (tid < 8) listlen[tid] = 0;
    __syncthreads();

    // wave-0 lane-private state: lane owns prototypes k = r*64 + lane
    float pn2r[8];
    unsigned idxp[8];
    if (wave == 0) {
#pragma unroll
        for (int r = 0; r < 8; ++r) {
            pn2r[r] = pn2_0[r * 64 + lane];
            idxp[r] = (unsigned)((r << 6) | lane);
        }
    }

    int ntiles = (ng + TILE - 1) / TILE;
    for (int T = 0; T < ntiles; ++T) {
        int j0 = T * TILE;
        int tlen = min(TILE, ng - j0);

        // ---- stage Dot0 tile (transposed) with mu^c scale fused ----
        {
            const float* basep = Dot + (size_t)(wave * 64) * NGMAX + j0 + lane;
            float* sb = sdot + lane * SDPITCH + wave * 64;
#pragma unroll 8
            for (int rr = 0; rr < 64; ++rr) {
                float sc = exp2f((float)rowcnt[wave * 64 + rr] * LOG2MU);
                sb[rr] = basep[(size_t)rr * NGMAX] * sc;
            }
        }
        // ---- corrections: wave streams its own flat list (deep MLP, no atomics) ----
        {
            int len = listlen[wave];
            const int* cl = clist + (size_t)wave * NGMAX;
            for (int i = 0; i < len; ++i) {
                int a = cl[i];
                int row = a & 511;
                int gq = (a >> 9) & 2047;
                int t = (a >> 20) & 4095;
                int c = rowcnt[row];
                float wq = OMU * exp2f((float)(c - 1 - gq) * LOG2MU);
                float gv = Gram[(size_t)t * NGMAX + j0 + lane];
                sdot[lane * SDPITCH + row] += wq * gv;
            }
        }
        // gram diag block + zn2
        {
            int t = tid >> 3, xo = (tid & 7) * 8;
            const float* src = Gram + (size_t)(j0 + t) * NGMAX + j0 + xo;
            float4 a = *(const float4*)(src);
            float4 b = *(const float4*)(src + 4);
            float* dst = sgram + t * 65 + xo;
            dst[0] = a.x; dst[1] = a.y; dst[2] = a.z; dst[3] = a.w;
            dst[4] = b.x; dst[5] = b.y; dst[6] = b.z; dst[7] = b.w;
        }
        if (tid < TILE) {
            szn2[tid] = (tid < tlen) ? zn2[gsteps[j0 + tid]] : 0.f;
        }
        __syncthreads();

        // ---- phase S (wave 0 only) ----
        if (wave == 0) {
            float d8[8];
#pragma unroll
            for (int r = 0; r < 8; ++r) d8[r] = sdot[r * 64 + lane];  // col 0
            float z2c = szn2[0];
            float gnc = sgram[1];  // G[0][1]
            int stw_reg = 0;

            for (int jl = 0; jl < tlen; ++jl) {
                // prefetch next column + scalars + RMW gram operand (all early)
                float pv[8];
                float nz2 = 0.f, ngn = 0.f;
                const bool hn = (jl + 1 < tlen);
                int xr = jl + 2 + lane;
                float grmw = sgram[jl * 65 + (xr < 64 ? xr : 63)];
                if (hn) {
                    const float* cb = sdot + (jl + 1) * SDPITCH;
#pragma unroll
                    for (int r = 0; r < 8; ++r) pv[r] = cb[r * 64 + lane];
                    nz2 = szn2[jl + 1];
                    ngn = sgram[(jl + 1) * 65 + (jl + 2)];
                } else {
#pragma unroll
                    for (int r = 0; r < 8; ++r) pv[r] = 0.f;
                }

                // packed-key argmin: d2 = (pn2+z2) - 2*dot >= 0, so raw float bits
                // order as u32; low 9 mantissa bits replaced by prototype index.
                unsigned kk[8];
#pragma unroll
                for (int r = 0; r < 8; ++r) {
                    float v = (pn2r[r] + z2c) - 2.f * d8[r];
                    kk[r] = (__float_as_uint(v) & 0xFFFFFE00u) | idxp[r];
                }
                unsigned a01 = min(kk[0], kk[1]), a23 = min(kk[2], kk[3]);
                unsigned a45 = min(kk[4], kk[5]), a67 = min(kk[6], kk[7]);
                unsigned km = wave_min_u(min(min(a01, a23), min(a45, a67)));
                int ks = (int)(km & 511u);
                int wlane = ks & 63, wr = ks >> 6;

                stw_reg = (lane == jl) ? ks : stw_reg;

                bool mine = (lane == wlane);
#pragma unroll
                for (int r = 0; r < 8; ++r) {
                    if (mine && r == wr) {
                        pn2r[r] = MU * MU * pn2r[r] + 2.f * MU * OMU * d8[r] + OMU * OMU * z2c;
                        pv[r] = MU * pv[r] + OMU * gnc;
                    }
                }

                // shift register pipeline BEFORE issuing the LDS RMW
#pragma unroll
                for (int r = 0; r < 8; ++r) d8[r] = pv[r];
                z2c = nz2; gnc = ngn;

                // winner-row update for in-tile columns >= jl+2 (off critical path)
                if (xr < tlen) {
                    float* dp = sdot + xr * SDPITCH + ks;
                    *dp = MU * *dp + OMU * grmw;
                }
            }

            // ---- post-pass: ranks, winlist append, per-wave correction lists ----
            int wj = stw_reg;
            bool valid = (lane < tlen);
            int myL = wj >> 6;
            int rank = 0, mrow = 0, lpos = 0, lcnt = 0;
            for (int i = 0; i < tlen; ++i) {
                int wi = __builtin_amdgcn_readlane(wj, i);
                if (valid && wi == wj) {
                    mrow++;
                    if (i < lane) rank++;
                }
                if (valid && (wi >> 6) == myL) {
                    lcnt++;
                    if (i < lane) lpos++;
                }
            }
            bool first = valid && (rank == 0);
            bool firstL = valid && (lpos == 0);
            int base = rowcnt[wj];      // read by all lanes before any update below
            int lbase = listlen[myL];
            if (valid) {
                int gq = base + rank;
                winlist[(size_t)wj * NGMAX + gq] = j0 + lane;
                clist[(size_t)myL * NGMAX + lbase + lpos] =
                    wj | (gq << 9) | ((j0 + lane) << 20);
            }
            if (first) rowcnt[wj] += mrow;
            if (firstL) listlen[myL] += lcnt;
        }
        __syncthreads();
    }

    cnt_out[tid] = rowcnt[tid];
}

// -------- materialize final prototypes via win lists (block per prototype) --------
__global__ void k_mat(const float* __restrict__ Z, const float* __restrict__ P0,
                      const int* __restrict__ gsteps, const int* __restrict__ winlist,
                      const int* __restrict__ cnt, float* __restrict__ Pn) {
    int k = blockIdx.x;
    int tid = threadIdx.x;
    int c = cnt[k];
    float bw = exp2f((float)c * LOG2MU);
    const float4* p0r = (const float4*)(P0 + (size_t)k * D_F);
    float4 a0 = p0r[tid], a1 = p0r[tid + 256];
    a0.x *= bw; a0.y *= bw; a0.z *= bw; a0.w *= bw;
    a1.x *= bw; a1.y *= bw; a1.z *= bw; a1.w *= bw;
    const int* wl = winlist + (size_t)k * NGMAX;
    float w = OMU;
    for (int q = c - 1; q >= 0; --q) {
        int t = wl[q];
        const float4* zr = (const float4*)(Z + (size_t)gsteps[t] * D_F);
        float4 z0 = zr[tid], z1 = zr[tid + 256];
        a0.x += w * z0.x; a0.y += w * z0.y; a0.z += w * z0.z; a0.w += w * z0.w;
        a1.x += w * z1.x; a1.y += w * z1.y; a1.z += w * z1.z; a1.w += w * z1.w;
        w *= MU;
    }
    float4* pnr = (float4*)(Pn + (size_t)k * D_F);
    pnr[tid] = a0;
    pnr[tid + 256] = a1;
}

// -------- top-3 nearest + pull-loss row sums (wave per row) --------
__global__ void k_top3(const float* __restrict__ Dotf, const float* __restrict__ pn2f,
                       const float* __restrict__ Z, const float* __restrict__ Pn,
                       float* __restrict__ rowsum) {
    int row = blockIdx.x * 4 + (threadIdx.x >> 6);
    int lane = threadIdx.x & 63;
    float bv0 = FLTMAX, bv1 = FLTMAX, bv2 = FLTMAX;
    int bi0 = IMAX, bi1 = IMAX, bi2 = IMAX;
    for (int t = 0; t < 8; ++t) {
        int k = lane + 64 * t;
        float v = pn2f[k] - 2.f * Dotf[(size_t)row * K_P + k];
        if (argless(v, k, bv0, bi0)) {
            bv2 = bv1; bi2 = bi1; bv1 = bv0; bi1 = bi0; bv0 = v; bi0 = k;
        } else if (argless(v, k, bv1, bi1)) {
            bv2 = bv1; bi2 = bi1; bv1 = v; bi1 = k;
        } else if (argless(v, k, bv2, bi2)) {
            bv2 = v; bi2 = k;
        }
    }
    for (int off = 32; off; off >>= 1) {
        float a0 = bv0, a1 = bv1, a2 = bv2;
        int x0 = bi0, x1 = bi1, x2 = bi2;
        float b0 = __shfl_xor(bv0, off), b1 = __shfl_xor(bv1, off), b2 = __shfl_xor(bv2, off);
        int y0 = __shfl_xor(bi0, off), y1 = __shfl_xor(bi1, off), y2 = __shfl_xor(bi2, off);
        float nv[3]; int ni[3];
#pragma unroll
        for (int s = 0; s < 3; ++s) {
            bool ta = argless(a0, x0, b0, y0);
            nv[s] = ta ? a0 : b0;
            ni[s] = ta ? x0 : y0;
            if (ta) { a0 = a1; x0 = x1; a1 = a2; x1 = x2; a2 = FLTMAX; x2 = IMAX; }
            else    { b0 = b1; y0 = y1; b1 = b2; y1 = y2; b2 = FLTMAX; y2 = IMAX; }
        }
        bv0 = nv[0]; bv1 = nv[1]; bv2 = nv[2];
        bi0 = ni[0]; bi1 = ni[1]; bi2 = ni[2];
    }
    const float* pa = Pn + (size_t)bi0 * D_F;
    const float* pb = Pn + (size_t)bi1 * D_F;
    const float* pc = Pn + (size_t)bi2 * D_F;
    const float* zr = Z + (size_t)row * D_F;
    const float third = 1.f / 3.f;
    float acc = 0.f;
    for (int d0 = lane * 4; d0 < D_F; d0 += 256) {
        float4 z = *(const float4*)(zr + d0);
        float4 A = *(const float4*)(pa + d0);
        float4 Bv = *(const float4*)(pb + d0);
        float4 C = *(const float4*)(pc + d0);
        float m, df;
        m = (A.x + Bv.x + C.x) * third; df = z.x - m; acc += df * df;
        m = (A.y + Bv.y + C.y) * third; df = z.y - m; acc += df * df;
        m = (A.z + Bv.z + C.z) * third; df = z.z - m; acc += df * df;
        m = (A.w + Bv.w + C.w) * third; df = z.w - m; acc += df * df;
    }
    for (int off = 32; off; off >>= 1) acc += __shfl_xor(acc, off);
    if (lane == 0) rowsum[row] = acc;
}

// -------- push-loss row values (wave per row) --------
__global__ void k_push(const float* __restrict__ Z, const float* __restrict__ m_a_used,
                       const float* __restrict__ zn2, const float* __restrict__ scal_f,
                       float* __restrict__ rowpush) {
    int row = blockIdx.x * 4 + (threadIdx.x >> 6);
    int lane = threadIdx.x & 63;
    const float* zr = Z + (size_t)row * D_F;
    float acc = 0.f;
    for (int d0 = lane * 4; d0 < D_F; d0 += 256) {
        float4 z = *(const float4*)(zr + d0);
        float4 m = *(const float4*)(m_a_used + d0);
        acc += z.x * m.x + z.y * m.y + z.z * m.z + z.w * m.w;
    }
    for (int off = 32; off; off >>= 1) acc += __shfl_xor(acc, off);
    if (lane == 0) {
        float d2 = zn2[row] - 2.f * acc + scal_f[0];
        float dist = sqrtf(fmaxf(d2, 0.f));
        rowpush[row] = fmaxf(1.f - dist, 0.f);
    }
}

// -------- final combine --------
__global__ void k_final(const float* __restrict__ rowsum, const float* __restrict__ rowpush,
                        const int* __restrict__ scal, float* __restrict__ out) {
    __shared__ float red[1024];
    int tid = threadIdx.x;
    float s = 0.f;
    for (int i = tid; i < B_N; i += 1024) s += rowsum[i];
    red[tid] = s;
    __syncthreads();
    for (int off = 512; off; off >>= 1) {
        if (tid < off) red[tid] += red[tid + off];
        __syncthreads();
    }
    float pull = red[0] / ((float)B_N * (float)D_F);
    __syncthreads();
    float p = 0.f;
    for (int i = tid; i < B_N; i += 1024) p += rowpush[i];
    red[tid] = p;
    __syncthreads();
    for (int off = 512; off; off >>= 1) {
        if (tid < off) red[tid] += red[tid + off];
        __syncthreads();
    }
    if (tid == 0) {
        float lpush = (scal[1] > 0) ? (red[0] / (float)B_N) : 0.f;
        out[0] = pull + 0.5f * lpush;
    }
}

extern "C" void kernel_launch(void* const* d_in, const int* in_sizes, int n_in,
                              void* d_out, int out_size, void* d_ws, size_t ws_size,
                              hipStream_t stream) {
    const float* Z = (const float*)d_in[0];
    const int* g = (const int*)d_in[1];
    const float* P0 = (const float*)d_in[2];
    const float* ma_in = (const float*)d_in[4];
    float* out = (float*)d_out;

    float* ws = (float*)d_ws;
    float* Gram = ws;                                   // 16M floats
    float* Dotf = ws;                                   // overlaps Gram (Gram dead by then)
    float* Dot = ws + (size_t)NGMAX * NGMAX;            // 512*4096 (read-only after GEMM)
    float* Pn = Dot + (size_t)K_P * NGMAX;              // 512*2048
    float* zn2 = Pn + (size_t)K_P * D_F;                // 4096
    float* pn2_0 = zn2 + B_N;                           // 512
    float* pn2f = pn2_0 + K_P;                          // 512
    float* anom_part = pn2f + K_P;                      // 32*2048
    float* m_a_used = anom_part + 32 * D_F;             // 2048
    float* rowsum = m_a_used + D_F;                     // 4096
    float* rowpush = rowsum + B_N;                      // 4096
    float* scal_f = rowpush + B_N;                      // 16
    int* gsteps = (int*)(scal_f + 16);                  // 4096
    int* cnt = gsteps + B_N;                            // 512
    int* scal = cnt + K_P;                              // 16
    int* winlist = scal + 16;                           // 512*4096 (8 MB)
    int* clist = winlist + (size_t)K_P * NGMAX;         // 8*4096 (128 KB)

    hipFuncSetAttribute((const void*)k_scan_tiled,
                        hipFuncAttributeMaxDynamicSharedMemorySize, SMEM_BYTES);

    k_prep<<<1, 1024, 0, stream>>>(g, gsteps, scal);
    k_rownorm<<<(B_N + 3) / 4, 256, 0, stream>>>(Z, zn2, B_N);
    k_rownorm<<<(K_P + 3) / 4, 256, 0, stream>>>(P0, pn2_0, K_P);
    k_colsum<<<dim3(D_F / 256, 32), 256, 0, stream>>>(Z, g, anom_part);
    k_fin_ma<<<1, 1024, 0, stream>>>(anom_part, ma_in, scal, m_a_used, scal_f);
    k_gemm<0><<<dim3(NGMAX / 64, (NGMAX + K_P) / 64), 256, 0, stream>>>(
        Z, P0, Pn, gsteps, scal, Gram, Dot, Dotf);
    k_scan_tiled<<<1, 512, SMEM_BYTES, stream>>>(Gram, Dot, pn2_0, zn2, gsteps, scal,
                                                 winlist, clist, cnt);
    k_mat<<<K_P, 256, 0, stream>>>(Z, P0, gsteps, winlist, cnt, Pn);
    k_rownorm<<<(K_P + 3) / 4, 256, 0, stream>>>(Pn, pn2f, K_P);
    k_gemm<1><<<dim3(K_P / 64, B_N / 64), 256, 0, stream>>>(
        Z, P0, Pn, gsteps, scal, Gram, Dot, Dotf);
    k_top3<<<B_N / 4, 256, 0, stream>>>(Dotf, pn2f, Z, Pn, rowsum);
    k_push<<<B_N / 4, 256, 0, stream>>>(Z, m_a_used, zn2, scal_f, rowpush);
    k_final<<<1, 1024, 0, stream>>>(rowsum, rowpush, scal, out);
}

// Round 10
// 2566.612 us; speedup vs baseline: 1.3404x; 1.0150x over previous
//
#include <hip/hip_runtime.h>
#include <math.h>

#define B_N 4096
#define D_F 2048
#define K_P 512
#define NGMAX 4096
#define MU 0.9f
#define OMU (1.0f - MU)
#define LOG2MU (-0.15200309344504997f)
#define FLTMAX 3.402823466e+38f
#define IMAX 0x7FFFFFFF
#define TILE 64
#define SDPITCH 513

// LDS carve (floats/ints)
#define SMEM_FLOATS (64 * SDPITCH + 64 * 65 + 64)
#define SMEM_INTS (512 + 16)
#define SMEM_BYTES ((SMEM_FLOATS + SMEM_INTS) * 4)

__device__ __forceinline__ bool argless(float v1, int i1, float v2, int i2) {
    return (v1 < v2) || (v1 == v2 && i1 < i2);
}

// u32 DPP min-reduce: lane 63 holds the wave min; readlane broadcasts.
template <int CTRL>
__device__ __forceinline__ unsigned dppmin_u(unsigned v) {
    unsigned t = (unsigned)__builtin_amdgcn_update_dpp((int)v, (int)v, CTRL, 0xf, 0xf, false);
    return min(v, t);
}
__device__ __forceinline__ unsigned wave_min_u(unsigned v) {
    v = dppmin_u<0x111>(v);  // row_shr:1
    v = dppmin_u<0x112>(v);  // row_shr:2
    v = dppmin_u<0x114>(v);  // row_shr:4
    v = dppmin_u<0x118>(v);  // row_shr:8
    v = dppmin_u<0x142>(v);  // row_bcast:15
    v = dppmin_u<0x143>(v);  // row_bcast:31
    return (unsigned)__builtin_amdgcn_readlane((int)v, 63);
}

// -------- prep: compact gated indices, counts --------
__global__ void k_prep(const int* __restrict__ g, int* __restrict__ gsteps,
                       int* __restrict__ scal) {
    __shared__ int s[1024];
    __shared__ int base;
    int tid = threadIdx.x;
    if (tid == 0) base = 0;
    __syncthreads();
    for (int c = 0; c < 4; ++c) {
        int i = c * 1024 + tid;
        int gi = (g[i] != 0) ? 1 : 0;
        s[tid] = gi;
        __syncthreads();
        for (int off = 1; off < 1024; off <<= 1) {
            int v = (tid >= off) ? s[tid - off] : 0;
            __syncthreads();
            s[tid] += v;
            __syncthreads();
        }
        int pos = base + s[tid] - 1;
        if (gi) gsteps[pos] = i;
        __syncthreads();
        if (tid == 1023) base += s[1023];
        __syncthreads();
    }
    if (tid == 0) { scal[0] = base; scal[1] = B_N - base; }
}

// -------- row squared norms (wave per row) --------
__global__ void k_rownorm(const float* __restrict__ src, float* __restrict__ dst, int nrows) {
    int row = blockIdx.x * 4 + (threadIdx.x >> 6);
    int lane = threadIdx.x & 63;
    if (row >= nrows) return;
    const float* p = src + (size_t)row * D_F;
    float acc = 0.f;
    for (int d0 = lane * 4; d0 < D_F; d0 += 256) {
        float4 v = *(const float4*)(p + d0);
        acc += v.x * v.x + v.y * v.y + v.z * v.z + v.w * v.w;
    }
    for (int off = 32; off; off >>= 1) acc += __shfl_xor(acc, off);
    if (lane == 0) dst[row] = acc;
}

// -------- anomaly column sums (partials) --------
__global__ void k_colsum(const float* __restrict__ Z, const int* __restrict__ g,
                         float* __restrict__ anom_part) {
    int d = blockIdx.x * 256 + threadIdx.x;
    int rc = blockIdx.y;
    float acc = 0.f;
    int r0 = rc * 128;
    for (int r = r0; r < r0 + 128; ++r) {
        if (g[r] == 0) acc += Z[(size_t)r * D_F + d];
    }
    anom_part[(size_t)rc * D_F + d] = acc;
}

// -------- finalize m_a --------
__global__ void k_fin_ma(const float* __restrict__ anom_part, const float* __restrict__ ma_in,
                         const int* __restrict__ scal, float* __restrict__ m_a_used,
                         float* __restrict__ scal_f) {
    __shared__ float red[1024];
    int tid = threadIdx.x;
    int na = scal[1];
    float m2 = 0.f;
    for (int dd = tid; dd < D_F; dd += 1024) {
        float s = 0.f;
        for (int c = 0; c < 32; ++c) s += anom_part[(size_t)c * D_F + dd];
        float v = (na > 0) ? (s / (float)na) : ma_in[dd];
        m_a_used[dd] = v;
        m2 += v * v;
    }
    red[tid] = m2;
    __syncthreads();
    for (int off = 512; off; off >>= 1) {
        if (tid < off) red[tid] += red[tid + off];
        __syncthreads();
    }
    if (tid == 0) scal_f[0] = red[0];
}

// -------- GEMM (NT: C = A * B^T), 64x64 tile, BK=16, 256 thr, 4x4 micro --------
template <int MODE>
__global__ void k_gemm(const float* __restrict__ Z, const float* __restrict__ P0,
                       const float* __restrict__ Pn, const int* __restrict__ gsteps,
                       const int* __restrict__ scal, float* __restrict__ Gram,
                       float* __restrict__ Dot, float* __restrict__ Dotf) {
    int ng = scal[0];
    int M = (MODE == 0) ? (ng + K_P) : B_N;
    int N = (MODE == 0) ? ng : K_P;
    int mb = blockIdx.y * 64, nb = blockIdx.x * 64;
    if (mb >= M || nb >= N) return;
    if (MODE == 0 && (mb + 64 <= ng) && (nb + 64 <= mb)) return;

    __shared__ float As[16][68];
    __shared__ float Bs[16][68];
    __shared__ const float* rowA[64];
    __shared__ const float* rowB[64];

    int tid = threadIdx.x;
    if (tid < 64) {
        int gm = mb + tid;
        const float* pa = nullptr;
        if (MODE == 0) {
            if (gm < ng) pa = Z + (size_t)gsteps[gm] * D_F;
            else if (gm < ng + K_P) pa = P0 + (size_t)(gm - ng) * D_F;
        } else {
            if (gm < B_N) pa = Z + (size_t)gm * D_F;
        }
        rowA[tid] = pa;
    } else if (tid < 128) {
        int t = tid - 64;
        int gn = nb + t;
        const float* pb = nullptr;
        if (MODE == 0) { if (gn < ng) pb = Z + (size_t)gsteps[gn] * D_F; }
        else { if (gn < K_P) pb = Pn + (size_t)gn * D_F; }
        rowB[t] = pb;
    }
    __syncthreads();

    int r = tid & 63, kq = tid >> 6;
    int tm = tid >> 4, tn = tid & 15;
    const float* pa = rowA[r];
    const float* pb = rowB[r];

    float acc[4][4] = {};
    for (int k0 = 0; k0 < D_F; k0 += 16) {
        float4 av = pa ? *(const float4*)(pa + k0 + kq * 4) : make_float4(0.f, 0.f, 0.f, 0.f);
        float4 bv = pb ? *(const float4*)(pb + k0 + kq * 4) : make_float4(0.f, 0.f, 0.f, 0.f);
        __syncthreads();
        As[kq * 4 + 0][r] = av.x; As[kq * 4 + 1][r] = av.y;
        As[kq * 4 + 2][r] = av.z; As[kq * 4 + 3][r] = av.w;
        Bs[kq * 4 + 0][r] = bv.x; Bs[kq * 4 + 1][r] = bv.y;
        Bs[kq * 4 + 2][r] = bv.z; Bs[kq * 4 + 3][r] = bv.w;
        __syncthreads();
#pragma unroll
        for (int kk = 0; kk < 16; ++kk) {
            float4 a = *(const float4*)&As[kk][tm * 4];
            float4 b = *(const float4*)&Bs[kk][tn * 4];
            float aa[4] = {a.x, a.y, a.z, a.w};
            float bb[4] = {b.x, b.y, b.z, b.w};
#pragma unroll
            for (int i = 0; i < 4; ++i)
#pragma unroll
                for (int j = 0; j < 4; ++j) acc[i][j] += aa[i] * bb[j];
        }
    }

#pragma unroll
    for (int i = 0; i < 4; ++i) {
        int gm = mb + tm * 4 + i;
        if (gm >= M) continue;
        float* crow;
        if (MODE == 0)
            crow = (gm < ng) ? (Gram + (size_t)gm * NGMAX) : (Dot + (size_t)(gm - ng) * NGMAX);
        else
            crow = Dotf + (size_t)gm * K_P;
#pragma unroll
        for (int j = 0; j < 4; ++j) {
            int gn = nb + tn * 4 + j;
            if (gn < N) crow[gn] = acc[i][j];
        }
    }
}

// -------- tiled sequential scan: packed-key argmin + deferred-RMW pipeline --------
__global__ __launch_bounds__(512, 1)
void k_scan_tiled(const float* __restrict__ Gram, const float* __restrict__ Dot,
                  const float* __restrict__ pn2_0, const float* __restrict__ zn2,
                  const int* __restrict__ gsteps, const int* __restrict__ scal,
                  int* __restrict__ winlist, int* __restrict__ clist,
                  int* __restrict__ cnt_out) {
    extern __shared__ char smem_raw[];
    float* sdot = (float*)smem_raw;             // [64][SDPITCH] transposed: sdot[x][k]
    float* sgram = sdot + 64 * SDPITCH;         // [64][65]
    float* szn2 = sgram + 64 * 65;              // [64]
    int* rowcnt = (int*)(szn2 + 64);            // [512] global win counts
    int* listlen = rowcnt + 512;                // [8] per-wave correction-list lengths

    int tid = threadIdx.x;
    int lane = tid & 63;
    int wave = tid >> 6;
    int ng = scal[0];

    rowcnt[tid] = 0;
    if (tid < 8) listlen[tid] = 0;
    __syncthreads();

    // wave-0 lane-private state: lane owns prototypes k = r*64 + lane
    float pn2r[8];
    unsigned idxp[8];
    if (wave == 0) {
#pragma unroll
        for (int r = 0; r < 8; ++r) {
            pn2r[r] = pn2_0[r * 64 + lane];
            idxp[r] = (unsigned)((r << 6) | lane);
        }
    }

    int ntiles = (ng + TILE - 1) / TILE;
    for (int T = 0; T < ntiles; ++T) {
        int j0 = T * TILE;
        int tlen = min(TILE, ng - j0);

        // ---- stage Dot0 tile (transposed) with mu^c scale fused ----
        {
            const float* basep = Dot + (size_t)(wave * 64) * NGMAX + j0 + lane;
            float* sb = sdot + lane * SDPITCH + wave * 64;
#pragma unroll 8
            for (int rr = 0; rr < 64; ++rr) {
                float sc = exp2f((float)rowcnt[wave * 64 + rr] * LOG2MU);
                sb[rr] = basep[(size_t)rr * NGMAX] * sc;
            }
        }
        // ---- corrections: wave streams its own flat list (deep MLP, no atomics) ----
        {
            int len = listlen[wave];
            const int* cl = clist + (size_t)wave * NGMAX;
            for (int i = 0; i < len; ++i) {
                int a = cl[i];
                int row = a & 511;
                int gq = (a >> 9) & 2047;
                int t = (a >> 20) & 4095;
                int c = rowcnt[row];
                float wq = OMU * exp2f((float)(c - 1 - gq) * LOG2MU);
                float gv = Gram[(size_t)t * NGMAX + j0 + lane];
                sdot[lane * SDPITCH + row] += wq * gv;
            }
        }
        // gram diag block + zn2
        {
            int t = tid >> 3, xo = (tid & 7) * 8;
            const float* src = Gram + (size_t)(j0 + t) * NGMAX + j0 + xo;
            float4 a = *(const float4*)(src);
            float4 b = *(const float4*)(src + 4);
            float* dst = sgram + t * 65 + xo;
            dst[0] = a.x; dst[1] = a.y; dst[2] = a.z; dst[3] = a.w;
            dst[4] = b.x; dst[5] = b.y; dst[6] = b.z; dst[7] = b.w;
        }
        if (tid < TILE) {
            szn2[tid] = (tid < tlen) ? zn2[gsteps[j0 + tid]] : 0.f;
        }
        __syncthreads();

        // ---- phase S (wave 0 only) ----
        if (wave == 0) {
            float d8[8];
#pragma unroll
            for (int r = 0; r < 8; ++r) d8[r] = sdot[r * 64 + lane];  // col 0
            float z2c = szn2[0];
            float gnc = sgram[1];  // G[0][1]
            int stw_reg = 0;
            // deferred-RMW state: write of step j lands at top of step j+1
            int pend_addr = -1;
            float pend_old = 0.f, pend_g = 0.f;

            for (int jl = 0; jl < tlen; ++jl) {
                // (0) flush previous step's RMW write (before any sdot read below).
                //     Step jl-1's write covers cols >= jl+1; the first reader is the
                //     prefetch of col jl+1 below — same-wave LDS is in-order.
                if (pend_addr >= 0) {
                    sdot[pend_addr] = MU * pend_old + OMU * pend_g;
                }
                // (1) prefetch next column + scalars + RMW gram operand
                float pv[8];
                float nz2 = 0.f, ngn = 0.f;
                const bool hn = (jl + 1 < tlen);
                int xr = jl + 2 + lane;
                float grmw = sgram[jl * 65 + (xr < 64 ? xr : 63)];
                if (hn) {
                    const float* cb = sdot + (jl + 1) * SDPITCH;
#pragma unroll
                    for (int r = 0; r < 8; ++r) pv[r] = cb[r * 64 + lane];
                    nz2 = szn2[jl + 1];
                    ngn = sgram[(jl + 1) * 65 + (jl + 2)];
                } else {
#pragma unroll
                    for (int r = 0; r < 8; ++r) pv[r] = 0.f;
                }

                // (2) packed-key argmin: d2 = (pn2+z2) - 2*dot >= 0 -> bits order as
                //     u32; low 9 mantissa bits replaced by prototype index.
                unsigned kk[8];
#pragma unroll
                for (int r = 0; r < 8; ++r) {
                    float v = (pn2r[r] + z2c) - 2.f * d8[r];
                    kk[r] = (__float_as_uint(v) & 0xFFFFFE00u) | idxp[r];
                }
                unsigned a01 = min(kk[0], kk[1]), a23 = min(kk[2], kk[3]);
                unsigned a45 = min(kk[4], kk[5]), a67 = min(kk[6], kk[7]);
                unsigned km = wave_min_u(min(min(a01, a23), min(a45, a67)));
                int ks = (int)(km & 511u);
                int wlane = ks & 63, wr = ks >> 6;

                // (3) issue the RMW read ASAP; its value is consumed at the NEXT
                //     iteration's flush, so its latency hides under the fixups.
                bool do_rmw = (xr < tlen);
                int rmw_addr = xr * SDPITCH + ks;
                float rmw_old = 0.f;
                if (do_rmw) rmw_old = sdot[rmw_addr];

                stw_reg = (lane == jl) ? ks : stw_reg;

                bool mine = (lane == wlane);
#pragma unroll
                for (int r = 0; r < 8; ++r) {
                    if (mine && r == wr) {
                        pn2r[r] = MU * MU * pn2r[r] + 2.f * MU * OMU * d8[r] + OMU * OMU * z2c;
                        pv[r] = MU * pv[r] + OMU * gnc;
                    }
                }

                // shift register pipeline
#pragma unroll
                for (int r = 0; r < 8; ++r) d8[r] = pv[r];
                z2c = nz2; gnc = ngn;

                // (4) arm deferred write
                pend_addr = do_rmw ? rmw_addr : -1;
                pend_old = rmw_old;
                pend_g = grmw;
            }
            if (pend_addr >= 0) {
                sdot[pend_addr] = MU * pend_old + OMU * pend_g;
            }

            // ---- post-pass: ranks, winlist append, per-wave correction lists ----
            int wj = stw_reg;
            bool valid = (lane < tlen);
            int myL = wj >> 6;
            int rank = 0, mrow = 0, lpos = 0, lcnt = 0;
            for (int i = 0; i < tlen; ++i) {
                int wi = __builtin_amdgcn_readlane(wj, i);
                if (valid && wi == wj) {
                    mrow++;
                    if (i < lane) rank++;
                }
                if (valid && (wi >> 6) == myL) {
                    lcnt++;
                    if (i < lane) lpos++;
                }
            }
            bool first = valid && (rank == 0);
            bool firstL = valid && (lpos == 0);
            int base = rowcnt[wj];      // read by all lanes before any update below
            int lbase = listlen[myL];
            if (valid) {
                int gq = base + rank;
                winlist[(size_t)wj * NGMAX + gq] = j0 + lane;
                clist[(size_t)myL * NGMAX + lbase + lpos] =
                    wj | (gq << 9) | ((j0 + lane) << 20);
            }
            if (first) rowcnt[wj] += mrow;
            if (firstL) listlen[myL] += lcnt;
        }
        __syncthreads();
    }

    cnt_out[tid] = rowcnt[tid];
}

// -------- materialize final prototypes via win lists (block per prototype) --------
__global__ void k_mat(const float* __restrict__ Z, const float* __restrict__ P0,
                      const int* __restrict__ gsteps, const int* __restrict__ winlist,
                      const int* __restrict__ cnt, float* __restrict__ Pn) {
    int k = blockIdx.x;
    int tid = threadIdx.x;
    int c = cnt[k];
    float bw = exp2f((float)c * LOG2MU);
    const float4* p0r = (const float4*)(P0 + (size_t)k * D_F);
    float4 a0 = p0r[tid], a1 = p0r[tid + 256];
    a0.x *= bw; a0.y *= bw; a0.z *= bw; a0.w *= bw;
    a1.x *= bw; a1.y *= bw; a1.z *= bw; a1.w *= bw;
    const int* wl = winlist + (size_t)k * NGMAX;
    float w = OMU;
    for (int q = c - 1; q >= 0; --q) {
        int t = wl[q];
        const float4* zr = (const float4*)(Z + (size_t)gsteps[t] * D_F);
        float4 z0 = zr[tid], z1 = zr[tid + 256];
        a0.x += w * z0.x; a0.y += w * z0.y; a0.z += w * z0.z; a0.w += w * z0.w;
        a1.x += w * z1.x; a1.y += w * z1.y; a1.z += w * z1.z; a1.w += w * z1.w;
        w *= MU;
    }
    float4* pnr = (float4*)(Pn + (size_t)k * D_F);
    pnr[tid] = a0;
    pnr[tid + 256] = a1;
}

// -------- top-3 nearest + pull-loss row sums (wave per row) --------
__global__ void k_top3(const float* __restrict__ Dotf, const float* __restrict__ pn2f,
                       const float* __restrict__ Z, const float* __restrict__ Pn,
                       float* __restrict__ rowsum) {
    int row = blockIdx.x * 4 + (threadIdx.x >> 6);
    int lane = threadIdx.x & 63;
    float bv0 = FLTMAX, bv1 = FLTMAX, bv2 = FLTMAX;
    int bi0 = IMAX, bi1 = IMAX, bi2 = IMAX;
    for (int t = 0; t < 8; ++t) {
        int k = lane + 64 * t;
        float v = pn2f[k] - 2.f * Dotf[(size_t)row * K_P + k];
        if (argless(v, k, bv0, bi0)) {
            bv2 = bv1; bi2 = bi1; bv1 = bv0; bi1 = bi0; bv0 = v; bi0 = k;
        } else if (argless(v, k, bv1, bi1)) {
            bv2 = bv1; bi2 = bi1; bv1 = v; bi1 = k;
        } else if (argless(v, k, bv2, bi2)) {
            bv2 = v; bi2 = k;
        }
    }
    for (int off = 32; off; off >>= 1) {
        float a0 = bv0, a1 = bv1, a2 = bv2;
        int x0 = bi0, x1 = bi1, x2 = bi2;
        float b0 = __shfl_xor(bv0, off), b1 = __shfl_xor(bv1, off), b2 = __shfl_xor(bv2, off);
        int y0 = __shfl_xor(bi0, off), y1 = __shfl_xor(bi1, off), y2 = __shfl_xor(bi2, off);
        float nv[3]; int ni[3];
#pragma unroll
        for (int s = 0; s < 3; ++s) {
            bool ta = argless(a0, x0, b0, y0);
            nv[s] = ta ? a0 : b0;
            ni[s] = ta ? x0 : y0;
            if (ta) { a0 = a1; x0 = x1; a1 = a2; x1 = x2; a2 = FLTMAX; x2 = IMAX; }
            else    { b0 = b1; y0 = y1; b1 = b2; y1 = y2; b2 = FLTMAX; y2 = IMAX; }
        }
        bv0 = nv[0]; bv1 = nv[1]; bv2 = nv[2];
        bi0 = ni[0]; bi1 = ni[1]; bi2 = ni[2];
    }
    const float* pa = Pn + (size_t)bi0 * D_F;
    const float* pb = Pn + (size_t)bi1 * D_F;
    const float* pc = Pn + (size_t)bi2 * D_F;
    const float* zr = Z + (size_t)row * D_F;
    const float third = 1.f / 3.f;
    float acc = 0.f;
    for (int d0 = lane * 4; d0 < D_F; d0 += 256) {
        float4 z = *(const float4*)(zr + d0);
        float4 A = *(const float4*)(pa + d0);
        float4 Bv = *(const float4*)(pb + d0);
        float4 C = *(const float4*)(pc + d0);
        float m, df;
        m = (A.x + Bv.x + C.x) * third; df = z.x - m; acc += df * df;
        m = (A.y + Bv.y + C.y) * third; df = z.y - m; acc += df * df;
        m = (A.z + Bv.z + C.z) * third; df = z.z - m; acc += df * df;
        m = (A.w + Bv.w + C.w) * third; df = z.w - m; acc += df * df;
    }
    for (int off = 32; off; off >>= 1) acc += __shfl_xor(acc, off);
    if (lane == 0) rowsum[row] = acc;
}

// -------- push-loss row values (wave per row) --------
__global__ void k_push(const float* __restrict__ Z, const float* __restrict__ m_a_used,
                       const float* __restrict__ zn2, const float* __restrict__ scal_f,
                       float* __restrict__ rowpush) {
    int row = blockIdx.x * 4 + (threadIdx.x >> 6);
    int lane = threadIdx.x & 63;
    const float* zr = Z + (size_t)row * D_F;
    float acc = 0.f;
    for (int d0 = lane * 4; d0 < D_F; d0 += 256) {
        float4 z = *(const float4*)(zr + d0);
        float4 m = *(const float4*)(m_a_used + d0);
        acc += z.x * m.x + z.y * m.y + z.z * m.z + z.w * m.w;
    }
    for (int off = 32; off; off >>= 1) acc += __shfl_xor(acc, off);
    if (lane == 0) {
        float d2 = zn2[row] - 2.f * acc + scal_f[0];
        float dist = sqrtf(fmaxf(d2, 0.f));
        rowpush[row] = fmaxf(1.f - dist, 0.f);
    }
}

// -------- final combine --------
__global__ void k_final(const float* __restrict__ rowsum, const float* __restrict__ rowpush,
                        const int* __restrict__ scal, float* __restrict__ out) {
    __shared__ float red[1024];
    int tid = threadIdx.x;
    float s = 0.f;
    for (int i = tid; i < B_N; i += 1024) s += rowsum[i];
    red[tid] = s;
    __syncthreads();
    for (int off = 512; off; off >>= 1) {
        if (tid < off) red[tid] += red[tid + off];
        __syncthreads();
    }
    float pull = red[0] / ((float)B_N * (float)D_F);
    __syncthreads();
    float p = 0.f;
    for (int i = tid; i < B_N; i += 1024) p += rowpush[i];
    red[tid] = p;
    __syncthreads();
    for (int off = 512; off; off >>= 1) {
        if (tid < off) red[tid] += red[tid + off];
        __syncthreads();
    }
    if (tid == 0) {
        float lpush = (scal[1] > 0) ? (red[0] / (float)B_N) : 0.f;
        out[0] = pull + 0.5f * lpush;
    }
}

extern "C" void kernel_launch(void* const* d_in, const int* in_sizes, int n_in,
                              void* d_out, int out_size, void* d_ws, size_t ws_size,
                              hipStream_t stream) {
    const float* Z = (const float*)d_in[0];
    const int* g = (const int*)d_in[1];
    const float* P0 = (const float*)d_in[2];
    const float* ma_in = (const float*)d_in[4];
    float* out = (float*)d_out;

    float* ws = (float*)d_ws;
    float* Gram = ws;                                   // 16M floats
    float* Dotf = ws;                                   // overlaps Gram (Gram dead by then)
    float* Dot = ws + (size_t)NGMAX * NGMAX;            // 512*4096 (read-only after GEMM)
    float* Pn = Dot + (size_t)K_P * NGMAX;              // 512*2048
    float* zn2 = Pn + (size_t)K_P * D_F;                // 4096
    float* pn2_0 = zn2 + B_N;                           // 512
    float* pn2f = pn2_0 + K_P;                          // 512
    float* anom_part = pn2f + K_P;                      // 32*2048
    float* m_a_used = anom_part + 32 * D_F;             // 2048
    float* rowsum = m_a_used + D_F;                     // 4096
    float* rowpush = rowsum + B_N;                      // 4096
    float* scal_f = rowpush + B_N;                      // 16
    int* gsteps = (int*)(scal_f + 16);                  // 4096
    int* cnt = gsteps + B_N;                            // 512
    int* scal = cnt + K_P;                              // 16
    int* winlist = scal + 16;                           // 512*4096 (8 MB)
    int* clist = winlist + (size_t)K_P * NGMAX;         // 8*4096 (128 KB)

    hipFuncSetAttribute((const void*)k_scan_tiled,
                        hipFuncAttributeMaxDynamicSharedMemorySize, SMEM_BYTES);

    k_prep<<<1, 1024, 0, stream>>>(g, gsteps, scal);
    k_rownorm<<<(B_N + 3) / 4, 256, 0, stream>>>(Z, zn2, B_N);
    k_rownorm<<<(K_P + 3) / 4, 256, 0, stream>>>(P0, pn2_0, K_P);
    k_colsum<<<dim3(D_F / 256, 32), 256, 0, stream>>>(Z, g, anom_part);
    k_fin_ma<<<1, 1024, 0, stream>>>(anom_part, ma_in, scal, m_a_used, scal_f);
    k_gemm<0><<<dim3(NGMAX / 64, (NGMAX + K_P) / 64), 256, 0, stream>>>(
        Z, P0, Pn, gsteps, scal, Gram, Dot, Dotf);
    k_scan_tiled<<<1, 512, SMEM_BYTES, stream>>>(Gram, Dot, pn2_0, zn2, gsteps, scal,
                                                 winlist, clist, cnt);
    k_mat<<<K_P, 256, 0, stream>>>(Z, P0, gsteps, winlist, cnt, Pn);
    k_rownorm<<<(K_P + 3) / 4, 256, 0, stream>>>(Pn, pn2f, K_P);
    k_gemm<1><<<dim3(K_P / 64, B_N / 64), 256, 0, stream>>>(
        Z, P0, Pn, gsteps, scal, Gram, Dot, Dotf);
    k_top3<<<B_N / 4, 256, 0, stream>>>(Dotf, pn2f, Z, Pn, rowsum);
    k_push<<<B_N / 4, 256, 0, stream>>>(Z, m_a_used, zn2, scal_f, rowpush);
    k_final<<<1, 1024, 0, stream>>>(rowsum, rowpush, scal, out);
}

// Round 11
// 2253.495 us; speedup vs baseline: 1.5267x; 1.1389x over previous
//
#include <hip/hip_runtime.h>
#include <math.h>

#define B_N 4096
#define D_F 2048
#define K_P 512
#define NGMAX 4096
#define MU 0.9f
#define OMU (1.0f - MU)
#define LOG2MU (-0.15200309344504997f)
#define FLTMAX 3.402823466e+38f
#define IMAX 0x7FFFFFFF
#define TILE 64
#define SDPITCH 513

// LDS carve (floats/ints)
#define SMEM_FLOATS (64 * SDPITCH + 64 * 65 + 64 + 512)
#define SMEM_INTS (512 + 16)
#define SMEM_BYTES ((SMEM_FLOATS + SMEM_INTS) * 4)

__device__ __forceinline__ bool argless(float v1, int i1, float v2, int i2) {
    return (v1 < v2) || (v1 == v2 && i1 < i2);
}

// u32 DPP min-reduce: lane 63 holds the wave min; readlane broadcasts.
template <int CTRL>
__device__ __forceinline__ unsigned dppmin_u(unsigned v) {
    unsigned t = (unsigned)__builtin_amdgcn_update_dpp((int)v, (int)v, CTRL, 0xf, 0xf, false);
    return min(v, t);
}
__device__ __forceinline__ unsigned wave_min_u(unsigned v) {
    v = dppmin_u<0x111>(v);  // row_shr:1
    v = dppmin_u<0x112>(v);  // row_shr:2
    v = dppmin_u<0x114>(v);  // row_shr:4
    v = dppmin_u<0x118>(v);  // row_shr:8
    v = dppmin_u<0x142>(v);  // row_bcast:15
    v = dppmin_u<0x143>(v);  // row_bcast:31
    return (unsigned)__builtin_amdgcn_readlane((int)v, 63);
}

// -------- prep: compact gated indices, counts --------
__global__ void k_prep(const int* __restrict__ g, int* __restrict__ gsteps,
                       int* __restrict__ scal) {
    __shared__ int s[1024];
    __shared__ int base;
    int tid = threadIdx.x;
    if (tid == 0) base = 0;
    __syncthreads();
    for (int c = 0; c < 4; ++c) {
        int i = c * 1024 + tid;
        int gi = (g[i] != 0) ? 1 : 0;
        s[tid] = gi;
        __syncthreads();
        for (int off = 1; off < 1024; off <<= 1) {
            int v = (tid >= off) ? s[tid - off] : 0;
            __syncthreads();
            s[tid] += v;
            __syncthreads();
        }
        int pos = base + s[tid] - 1;
        if (gi) gsteps[pos] = i;
        __syncthreads();
        if (tid == 1023) base += s[1023];
        __syncthreads();
    }
    if (tid == 0) { scal[0] = base; scal[1] = B_N - base; }
}

// -------- row squared norms (wave per row) --------
__global__ void k_rownorm(const float* __restrict__ src, float* __restrict__ dst, int nrows) {
    int row = blockIdx.x * 4 + (threadIdx.x >> 6);
    int lane = threadIdx.x & 63;
    if (row >= nrows) return;
    const float* p = src + (size_t)row * D_F;
    float acc = 0.f;
    for (int d0 = lane * 4; d0 < D_F; d0 += 256) {
        float4 v = *(const float4*)(p + d0);
        acc += v.x * v.x + v.y * v.y + v.z * v.z + v.w * v.w;
    }
    for (int off = 32; off; off >>= 1) acc += __shfl_xor(acc, off);
    if (lane == 0) dst[row] = acc;
}

// -------- anomaly column sums (partials) --------
__global__ void k_colsum(const float* __restrict__ Z, const int* __restrict__ g,
                         float* __restrict__ anom_part) {
    int d = blockIdx.x * 256 + threadIdx.x;
    int rc = blockIdx.y;
    float acc = 0.f;
    int r0 = rc * 128;
    for (int r = r0; r < r0 + 128; ++r) {
        if (g[r] == 0) acc += Z[(size_t)r * D_F + d];
    }
    anom_part[(size_t)rc * D_F + d] = acc;
}

// -------- finalize m_a --------
__global__ void k_fin_ma(const float* __restrict__ anom_part, const float* __restrict__ ma_in,
                         const int* __restrict__ scal, float* __restrict__ m_a_used,
                         float* __restrict__ scal_f) {
    __shared__ float red[1024];
    int tid = threadIdx.x;
    int na = scal[1];
    float m2 = 0.f;
    for (int dd = tid; dd < D_F; dd += 1024) {
        float s = 0.f;
        for (int c = 0; c < 32; ++c) s += anom_part[(size_t)c * D_F + dd];
        float v = (na > 0) ? (s / (float)na) : ma_in[dd];
        m_a_used[dd] = v;
        m2 += v * v;
    }
    red[tid] = m2;
    __syncthreads();
    for (int off = 512; off; off >>= 1) {
        if (tid < off) red[tid] += red[tid + off];
        __syncthreads();
    }
    if (tid == 0) scal_f[0] = red[0];
}

// -------- GEMM (NT: C = A * B^T), 64x64 tile, BK=16, 256 thr, 4x4 micro --------
template <int MODE>
__global__ void k_gemm(const float* __restrict__ Z, const float* __restrict__ P0,
                       const float* __restrict__ Pn, const int* __restrict__ gsteps,
                       const int* __restrict__ scal, float* __restrict__ Gram,
                       float* __restrict__ Dot, float* __restrict__ Dotf) {
    int ng = scal[0];
    int M = (MODE == 0) ? (ng + K_P) : B_N;
    int N = (MODE == 0) ? ng : K_P;
    int mb = blockIdx.y * 64, nb = blockIdx.x * 64;
    if (mb >= M || nb >= N) return;
    if (MODE == 0 && (mb + 64 <= ng) && (nb + 64 <= mb)) return;

    __shared__ float As[16][68];
    __shared__ float Bs[16][68];
    __shared__ const float* rowA[64];
    __shared__ const float* rowB[64];

    int tid = threadIdx.x;
    if (tid < 64) {
        int gm = mb + tid;
        const float* pa = nullptr;
        if (MODE == 0) {
            if (gm < ng) pa = Z + (size_t)gsteps[gm] * D_F;
            else if (gm < ng + K_P) pa = P0 + (size_t)(gm - ng) * D_F;
        } else {
            if (gm < B_N) pa = Z + (size_t)gm * D_F;
        }
        rowA[tid] = pa;
    } else if (tid < 128) {
        int t = tid - 64;
        int gn = nb + t;
        const float* pb = nullptr;
        if (MODE == 0) { if (gn < ng) pb = Z + (size_t)gsteps[gn] * D_F; }
        else { if (gn < K_P) pb = Pn + (size_t)gn * D_F; }
        rowB[t] = pb;
    }
    __syncthreads();

    int r = tid & 63, kq = tid >> 6;
    int tm = tid >> 4, tn = tid & 15;
    const float* pa = rowA[r];
    const float* pb = rowB[r];

    float acc[4][4] = {};
    for (int k0 = 0; k0 < D_F; k0 += 16) {
        float4 av = pa ? *(const float4*)(pa + k0 + kq * 4) : make_float4(0.f, 0.f, 0.f, 0.f);
        float4 bv = pb ? *(const float4*)(pb + k0 + kq * 4) : make_float4(0.f, 0.f, 0.f, 0.f);
        __syncthreads();
        As[kq * 4 + 0][r] = av.x; As[kq * 4 + 1][r] = av.y;
        As[kq * 4 + 2][r] = av.z; As[kq * 4 + 3][r] = av.w;
        Bs[kq * 4 + 0][r] = bv.x; Bs[kq * 4 + 1][r] = bv.y;
        Bs[kq * 4 + 2][r] = bv.z; Bs[kq * 4 + 3][r] = bv.w;
        __syncthreads();
#pragma unroll
        for (int kk = 0; kk < 16; ++kk) {
            float4 a = *(const float4*)&As[kk][tm * 4];
            float4 b = *(const float4*)&Bs[kk][tn * 4];
            float aa[4] = {a.x, a.y, a.z, a.w};
            float bb[4] = {b.x, b.y, b.z, b.w};
#pragma unroll
            for (int i = 0; i < 4; ++i)
#pragma unroll
                for (int j = 0; j < 4; ++j) acc[i][j] += aa[i] * bb[j];
        }
    }

#pragma unroll
    for (int i = 0; i < 4; ++i) {
        int gm = mb + tm * 4 + i;
        if (gm >= M) continue;
        float* crow;
        if (MODE == 0)
            crow = (gm < ng) ? (Gram + (size_t)gm * NGMAX) : (Dot + (size_t)(gm - ng) * NGMAX);
        else
            crow = Dotf + (size_t)gm * K_P;
#pragma unroll
        for (int j = 0; j < 4; ++j) {
            int gn = nb + tn * 4 + j;
            if (gn < N) crow[gn] = acc[i][j];
        }
    }
}

// -------- tiled sequential scan: packed-key argmin + batched corrections --------
__global__ __launch_bounds__(512, 1)
void k_scan_tiled(const float* __restrict__ Gram, const float* __restrict__ Dot,
                  const float* __restrict__ pn2_0, const float* __restrict__ zn2,
                  const int* __restrict__ gsteps, const int* __restrict__ scal,
                  int* __restrict__ winlist, int* __restrict__ clist,
                  int* __restrict__ cnt_out) {
    extern __shared__ char smem_raw[];
    float* sdot = (float*)smem_raw;             // [64][SDPITCH] transposed: sdot[x][k]
    float* sgram = sdot + 64 * SDPITCH;         // [64][65]
    float* szn2 = sgram + 64 * 65;              // [64]
    float* sscale = szn2 + 64;                  // [512] mu^rowcnt per row
    int* rowcnt = (int*)(sscale + 512);         // [512] global win counts
    int* listlen = rowcnt + 512;                // [8] per-wave correction-list lengths

    int tid = threadIdx.x;
    int lane = tid & 63;
    int wave = tid >> 6;
    int ng = scal[0];

    rowcnt[tid] = 0;
    if (tid < 8) listlen[tid] = 0;
    __syncthreads();

    // wave-0 lane-private state: lane owns prototypes k = r*64 + lane
    float pn2r[8];
    unsigned idxp[8];
    if (wave == 0) {
#pragma unroll
        for (int r = 0; r < 8; ++r) {
            pn2r[r] = pn2_0[r * 64 + lane];
            idxp[r] = (unsigned)((r << 6) | lane);
        }
    }

    int ntiles = (ng + TILE - 1) / TILE;
    for (int T = 0; T < ntiles; ++T) {
        int j0 = T * TILE;
        int tlen = min(TILE, ng - j0);

        // per-row scale (same-wave write/read: thread tid serves wave tid>>6)
        sscale[tid] = exp2f((float)rowcnt[tid] * LOG2MU);

        // ---- stage Dot0 tile (transposed) with mu^c scale fused ----
        {
            const float* basep = Dot + (size_t)(wave * 64) * NGMAX + j0 + lane;
            float* sb = sdot + lane * SDPITCH + wave * 64;
            const float* ss = sscale + wave * 64;
#pragma unroll 16
            for (int rr = 0; rr < 64; ++rr) {
                sb[rr] = basep[(size_t)rr * NGMAX] * ss[rr];
            }
        }
        // ---- corrections: wave streams its own flat list, batched (MLP=8) ----
        {
            int len = listlen[wave];
            const int* cl = clist + (size_t)wave * NGMAX;
            int i = 0;
            for (; i + 8 <= len; i += 8) {
                int a[8];
#pragma unroll
                for (int q = 0; q < 8; ++q) a[q] = cl[i + q];
                float gv[8];
#pragma unroll
                for (int q = 0; q < 8; ++q) {
                    int t = (a[q] >> 20) & 4095;
                    gv[q] = Gram[(size_t)t * NGMAX + j0 + lane];
                }
                float wq[8];
#pragma unroll
                for (int q = 0; q < 8; ++q) {
                    int row = a[q] & 511;
                    int gq = (a[q] >> 9) & 2047;
                    int c = rowcnt[row];
                    wq[q] = OMU * exp2f((float)(c - 1 - gq) * LOG2MU);
                }
#pragma unroll
                for (int q = 0; q < 8; ++q) {
                    int row = a[q] & 511;
                    sdot[lane * SDPITCH + row] += wq[q] * gv[q];
                }
            }
            for (; i < len; ++i) {
                int a = cl[i];
                int row = a & 511;
                int gq = (a >> 9) & 2047;
                int t = (a >> 20) & 4095;
                int c = rowcnt[row];
                float wqs = OMU * exp2f((float)(c - 1 - gq) * LOG2MU);
                float gv = Gram[(size_t)t * NGMAX + j0 + lane];
                sdot[lane * SDPITCH + row] += wqs * gv;
            }
        }
        // gram diag block + zn2
        {
            int t = tid >> 3, xo = (tid & 7) * 8;
            const float* src = Gram + (size_t)(j0 + t) * NGMAX + j0 + xo;
            float4 a = *(const float4*)(src);
            float4 b = *(const float4*)(src + 4);
            float* dst = sgram + t * 65 + xo;
            dst[0] = a.x; dst[1] = a.y; dst[2] = a.z; dst[3] = a.w;
            dst[4] = b.x; dst[5] = b.y; dst[6] = b.z; dst[7] = b.w;
        }
        if (tid < TILE) {
            szn2[tid] = (tid < tlen) ? zn2[gsteps[j0 + tid]] : 0.f;
        }
        __syncthreads();

        // ---- phase S (wave 0 only) ----
        if (wave == 0) {
            float d8[8];
#pragma unroll
            for (int r = 0; r < 8; ++r) d8[r] = sdot[r * 64 + lane];  // col 0
            float z2c = szn2[0];
            float gnc = sgram[1];  // G[0][1]
            int stw_reg = 0;
            // deferred-RMW state: write of step j lands at top of step j+1
            int pend_addr = -1;
            float pend_old = 0.f, pend_g = 0.f;

            for (int jl = 0; jl < tlen; ++jl) {
                // (0) flush previous step's RMW write (before any sdot read below)
                if (pend_addr >= 0) {
                    sdot[pend_addr] = MU * pend_old + OMU * pend_g;
                }
                // (1) prefetch next column + scalars + RMW gram operand
                float pv[8];
                float nz2 = 0.f, ngn = 0.f;
                const bool hn = (jl + 1 < tlen);
                int xr = jl + 2 + lane;
                float grmw = sgram[jl * 65 + (xr < 64 ? xr : 63)];
                if (hn) {
                    const float* cb = sdot + (jl + 1) * SDPITCH;
#pragma unroll
                    for (int r = 0; r < 8; ++r) pv[r] = cb[r * 64 + lane];
                    nz2 = szn2[jl + 1];
                    ngn = sgram[(jl + 1) * 65 + (jl + 2)];
                } else {
#pragma unroll
                    for (int r = 0; r < 8; ++r) pv[r] = 0.f;
                }

                // (2) packed-key argmin
                unsigned kk[8];
#pragma unroll
                for (int r = 0; r < 8; ++r) {
                    float v = (pn2r[r] + z2c) - 2.f * d8[r];
                    kk[r] = (__float_as_uint(v) & 0xFFFFFE00u) | idxp[r];
                }
                unsigned a01 = min(kk[0], kk[1]), a23 = min(kk[2], kk[3]);
                unsigned a45 = min(kk[4], kk[5]), a67 = min(kk[6], kk[7]);
                unsigned km = wave_min_u(min(min(a01, a23), min(a45, a67)));
                int ks = (int)(km & 511u);
                int wlane = ks & 63, wr = ks >> 6;

                // (3) issue the RMW read ASAP; consumed at next iteration's flush
                bool do_rmw = (xr < tlen);
                int rmw_addr = xr * SDPITCH + ks;
                float rmw_old = 0.f;
                if (do_rmw) rmw_old = sdot[rmw_addr];

                stw_reg = (lane == jl) ? ks : stw_reg;

                bool mine = (lane == wlane);
#pragma unroll
                for (int r = 0; r < 8; ++r) {
                    if (mine && r == wr) {
                        pn2r[r] = MU * MU * pn2r[r] + 2.f * MU * OMU * d8[r] + OMU * OMU * z2c;
                        pv[r] = MU * pv[r] + OMU * gnc;
                    }
                }

                // shift register pipeline
#pragma unroll
                for (int r = 0; r < 8; ++r) d8[r] = pv[r];
                z2c = nz2; gnc = ngn;

                // (4) arm deferred write
                pend_addr = do_rmw ? rmw_addr : -1;
                pend_old = rmw_old;
                pend_g = grmw;
            }
            if (pend_addr >= 0) {
                sdot[pend_addr] = MU * pend_old + OMU * pend_g;
            }

            // ---- post-pass: ranks, winlist append, per-wave correction lists ----
            int wj = stw_reg;
            bool valid = (lane < tlen);
            int myL = wj >> 6;
            int rank = 0, mrow = 0, lpos = 0, lcnt = 0;
            for (int i = 0; i < tlen; ++i) {
                int wi = __builtin_amdgcn_readlane(wj, i);
                if (valid && wi == wj) {
                    mrow++;
                    if (i < lane) rank++;
                }
                if (valid && (wi >> 6) == myL) {
                    lcnt++;
                    if (i < lane) lpos++;
                }
            }
            bool first = valid && (rank == 0);
            bool firstL = valid && (lpos == 0);
            int base = rowcnt[wj];      // read by all lanes before any update below
            int lbase = listlen[myL];
            if (valid) {
                int gq = base + rank;
                winlist[(size_t)wj * NGMAX + gq] = j0 + lane;
                clist[(size_t)myL * NGMAX + lbase + lpos] =
                    wj | (gq << 9) | ((j0 + lane) << 20);
            }
            if (first) rowcnt[wj] += mrow;
            if (firstL) listlen[myL] += lcnt;
        }
        __syncthreads();
    }

    cnt_out[tid] = rowcnt[tid];
}

// -------- materialize final prototypes via win lists (block per prototype) --------
__global__ void k_mat(const float* __restrict__ Z, const float* __restrict__ P0,
                      const int* __restrict__ gsteps, const int* __restrict__ winlist,
                      const int* __restrict__ cnt, float* __restrict__ Pn) {
    int k = blockIdx.x;
    int tid = threadIdx.x;
    int c = cnt[k];
    float bw = exp2f((float)c * LOG2MU);
    const float4* p0r = (const float4*)(P0 + (size_t)k * D_F);
    float4 a0 = p0r[tid], a1 = p0r[tid + 256];
    a0.x *= bw; a0.y *= bw; a0.z *= bw; a0.w *= bw;
    a1.x *= bw; a1.y *= bw; a1.z *= bw; a1.w *= bw;
    const int* wl = winlist + (size_t)k * NGMAX;
    float w = OMU;
    for (int q = c - 1; q >= 0; --q) {
        int t = wl[q];
        const float4* zr = (const float4*)(Z + (size_t)gsteps[t] * D_F);
        float4 z0 = zr[tid], z1 = zr[tid + 256];
        a0.x += w * z0.x; a0.y += w * z0.y; a0.z += w * z0.z; a0.w += w * z0.w;
        a1.x += w * z1.x; a1.y += w * z1.y; a1.z += w * z1.z; a1.w += w * z1.w;
        w *= MU;
    }
    float4* pnr = (float4*)(Pn + (size_t)k * D_F);
    pnr[tid] = a0;
    pnr[tid + 256] = a1;
}

// -------- top-3 nearest + pull-loss row sums (wave per row) --------
__global__ void k_top3(const float* __restrict__ Dotf, const float* __restrict__ pn2f,
                       const float* __restrict__ Z, const float* __restrict__ Pn,
                       float* __restrict__ rowsum) {
    int row = blockIdx.x * 4 + (threadIdx.x >> 6);
    int lane = threadIdx.x & 63;
    float bv0 = FLTMAX, bv1 = FLTMAX, bv2 = FLTMAX;
    int bi0 = IMAX, bi1 = IMAX, bi2 = IMAX;
    for (int t = 0; t < 8; ++t) {
        int k = lane + 64 * t;
        float v = pn2f[k] - 2.f * Dotf[(size_t)row * K_P + k];
        if (argless(v, k, bv0, bi0)) {
            bv2 = bv1; bi2 = bi1; bv1 = bv0; bi1 = bi0; bv0 = v; bi0 = k;
        } else if (argless(v, k, bv1, bi1)) {
            bv2 = bv1; bi2 = bi1; bv1 = v; bi1 = k;
        } else if (argless(v, k, bv2, bi2)) {
            bv2 = v; bi2 = k;
        }
    }
    for (int off = 32; off; off >>= 1) {
        float a0 = bv0, a1 = bv1, a2 = bv2;
        int x0 = bi0, x1 = bi1, x2 = bi2;
        float b0 = __shfl_xor(bv0, off), b1 = __shfl_xor(bv1, off), b2 = __shfl_xor(bv2, off);
        int y0 = __shfl_xor(bi0, off), y1 = __shfl_xor(bi1, off), y2 = __shfl_xor(bi2, off);
        float nv[3]; int ni[3];
#pragma unroll
        for (int s = 0; s < 3; ++s) {
            bool ta = argless(a0, x0, b0, y0);
            nv[s] = ta ? a0 : b0;
            ni[s] = ta ? x0 : y0;
            if (ta) { a0 = a1; x0 = x1; a1 = a2; x1 = x2; a2 = FLTMAX; x2 = IMAX; }
            else    { b0 = b1; y0 = y1; b1 = b2; y1 = y2; b2 = FLTMAX; y2 = IMAX; }
        }
        bv0 = nv[0]; bv1 = nv[1]; bv2 = nv[2];
        bi0 = ni[0]; bi1 = ni[1]; bi2 = ni[2];
    }
    const float* pa = Pn + (size_t)bi0 * D_F;
    const float* pb = Pn + (size_t)bi1 * D_F;
    const float* pc = Pn + (size_t)bi2 * D_F;
    const float* zr = Z + (size_t)row * D_F;
    const float third = 1.f / 3.f;
    float acc = 0.f;
    for (int d0 = lane * 4; d0 < D_F; d0 += 256) {
        float4 z = *(const float4*)(zr + d0);
        float4 A = *(const float4*)(pa + d0);
        float4 Bv = *(const float4*)(pb + d0);
        float4 C = *(const float4*)(pc + d0);
        float m, df;
        m = (A.x + Bv.x + C.x) * third; df = z.x - m; acc += df * df;
        m = (A.y + Bv.y + C.y) * third; df = z.y - m; acc += df * df;
        m = (A.z + Bv.z + C.z) * third; df = z.z - m; acc += df * df;
        m = (A.w + Bv.w + C.w) * third; df = z.w - m; acc += df * df;
    }
    for (int off = 32; off; off >>= 1) acc += __shfl_xor(acc, off);
    if (lane == 0) rowsum[row] = acc;
}

// -------- push-loss row values (wave per row) --------
__global__ void k_push(const float* __restrict__ Z, const float* __restrict__ m_a_used,
                       const float* __restrict__ zn2, const float* __restrict__ scal_f,
                       float* __restrict__ rowpush) {
    int row = blockIdx.x * 4 + (threadIdx.x >> 6);
    int lane = threadIdx.x & 63;
    const float* zr = Z + (size_t)row * D_F;
    float acc = 0.f;
    for (int d0 = lane * 4; d0 < D_F; d0 += 256) {
        float4 z = *(const float4*)(zr + d0);
        float4 m = *(const float4*)(m_a_used + d0);
        acc += z.x * m.x + z.y * m.y + z.z * m.z + z.w * m.w;
    }
    for (int off = 32; off; off >>= 1) acc += __shfl_xor(acc, off);
    if (lane == 0) {
        float d2 = zn2[row] - 2.f * acc + scal_f[0];
        float dist = sqrtf(fmaxf(d2, 0.f));
        rowpush[row] = fmaxf(1.f - dist, 0.f);
    }
}

// -------- final combine --------
__global__ void k_final(const float* __restrict__ rowsum, const float* __restrict__ rowpush,
                        const int* __restrict__ scal, float* __restrict__ out) {
    __shared__ float red[1024];
    int tid = threadIdx.x;
    float s = 0.f;
    for (int i = tid; i < B_N; i += 1024) s += rowsum[i];
    red[tid] = s;
    __syncthreads();
    for (int off = 512; off; off >>= 1) {
        if (tid < off) red[tid] += red[tid + off];
        __syncthreads();
    }
    float pull = red[0] / ((float)B_N * (float)D_F);
    __syncthreads();
    float p = 0.f;
    for (int i = tid; i < B_N; i += 1024) p += rowpush[i];
    red[tid] = p;
    __syncthreads();
    for (int off = 512; off; off >>= 1) {
        if (tid < off) red[tid] += red[tid + off];
        __syncthreads();
    }
    if (tid == 0) {
        float lpush = (scal[1] > 0) ? (red[0] / (float)B_N) : 0.f;
        out[0] = pull + 0.5f * lpush;
    }
}

extern "C" void kernel_launch(void* const* d_in, const int* in_sizes, int n_in,
                              void* d_out, int out_size, void* d_ws, size_t ws_size,
                              hipStream_t stream) {
    const float* Z = (const float*)d_in[0];
    const int* g = (const int*)d_in[1];
    const float* P0 = (const float*)d_in[2];
    const float* ma_in = (const float*)d_in[4];
    float* out = (float*)d_out;

    float* ws = (float*)d_ws;
    float* Gram = ws;                                   // 16M floats
    float* Dotf = ws;                                   // overlaps Gram (Gram dead by then)
    float* Dot = ws + (size_t)NGMAX * NGMAX;            // 512*4096 (read-only after GEMM)
    float* Pn = Dot + (size_t)K_P * NGMAX;              // 512*2048
    float* zn2 = Pn + (size_t)K_P * D_F;                // 4096
    float* pn2_0 = zn2 + B_N;                           // 512
    float* pn2f = pn2_0 + K_P;                          // 512
    float* anom_part = pn2f + K_P;                      // 32*2048
    float* m_a_used = anom_part + 32 * D_F;             // 2048
    float* rowsum = m_a_used + D_F;                     // 4096
    float* rowpush = rowsum + B_N;                      // 4096
    float* scal_f = rowpush + B_N;                      // 16
    int* gsteps = (int*)(scal_f + 16);                  // 4096
    int* cnt = gsteps + B_N;                            // 512
    int* scal = cnt + K_P;                              // 16
    int* winlist = scal + 16;                           // 512*4096 (8 MB)
    int* clist = winlist + (size_t)K_P * NGMAX;         // 8*4096 (128 KB)

    hipFuncSetAttribute((const void*)k_scan_tiled,
                        hipFuncAttributeMaxDynamicSharedMemorySize, SMEM_BYTES);

    k_prep<<<1, 1024, 0, stream>>>(g, gsteps, scal);
    k_rownorm<<<(B_N + 3) / 4, 256, 0, stream>>>(Z, zn2, B_N);
    k_rownorm<<<(K_P + 3) / 4, 256, 0, stream>>>(P0, pn2_0, K_P);
    k_colsum<<<dim3(D_F / 256, 32), 256, 0, stream>>>(Z, g, anom_part);
    k_fin_ma<<<1, 1024, 0, stream>>>(anom_part, ma_in, scal, m_a_used, scal_f);
    k_gemm<0><<<dim3(NGMAX / 64, (NGMAX + K_P) / 64), 256, 0, stream>>>(
        Z, P0, Pn, gsteps, scal, Gram, Dot, Dotf);
    k_scan_tiled<<<1, 512, SMEM_BYTES, stream>>>(Gram, Dot, pn2_0, zn2, gsteps, scal,
                                                 winlist, clist, cnt);
    k_mat<<<K_P, 256, 0, stream>>>(Z, P0, gsteps, winlist, cnt, Pn);
    k_rownorm<<<(K_P + 3) / 4, 256, 0, stream>>>(Pn, pn2f, K_P);
    k_gemm<1><<<dim3(K_P / 64, B_N / 64), 256, 0, stream>>>(
        Z, P0, Pn, gsteps, scal, Gram, Dot, Dotf);
    k_top3<<<B_N / 4, 256, 0, stream>>>(Dotf, pn2f, Z, Pn, rowsum);
    k_push<<<B_N / 4, 256, 0, stream>>>(Z, m_a_used, zn2, scal_f, rowpush);
    k_final<<<1, 1024, 0, stream>>>(rowsum, rowpush, scal, out);
}